// Round 12
// baseline (491.539 us; speedup 1.0000x reference)
//
#include <hip/hip_runtime.h>

// ---------------- problem constants ----------------
#define Q_   25600
#define C_   256
#define NH_  8
#define HD_  32
#define NP_  4
#define LC_  2
#define HW_  160          // H == W == 160

#define QC   (Q_ * C_)            // 6,553,600
#define VC   (2 * QC)             // 13,107,200
#define REFN (Q_ * LC_ * 2)       // 102,400

typedef unsigned short ushort_t;
typedef __attribute__((ext_vector_type(8))) short short8;
typedef __attribute__((ext_vector_type(4))) float f32x4;

// ---------------- bf16 helpers ----------------
__device__ __forceinline__ float b2f(ushort_t u) {
    union { unsigned int u32; float f; } c; c.u32 = ((unsigned int)u) << 16; return c.f;
}
__device__ __forceinline__ ushort_t f2b(float f) {
    union { float f; unsigned int u32; } c; c.f = f;
    unsigned int u = c.u32;
    return (ushort_t)((u + 0x7FFFu + ((u >> 16) & 1u)) >> 16);
}
__device__ __forceinline__ unsigned int pack2(float lo, float hi){
    return (unsigned int)f2b(lo) | ((unsigned int)f2b(hi) << 16);
}
__device__ __forceinline__ short8 pack8(float4 a, float4 b){
    union { short8 s; ushort_t u[8]; } r;
    r.u[0]=f2b(a.x); r.u[1]=f2b(a.y); r.u[2]=f2b(a.z); r.u[3]=f2b(a.w);
    r.u[4]=f2b(b.x); r.u[5]=f2b(b.y); r.u[6]=f2b(b.z); r.u[7]=f2b(b.w);
    return r.s;
}
__device__ __forceinline__ float uasf(unsigned int u){
    union { unsigned int u32; float f; } c; c.u32 = u; return c.f;
}
// unpack 4 bf16 (packed in uint2) -> 4 floats
__device__ __forceinline__ float4 unpk4(uint2 u){
    float4 r;
    r.x = uasf(u.x << 16); r.y = uasf(u.x & 0xFFFF0000u);
    r.z = uasf(u.y << 16); r.w = uasf(u.y & 0xFFFF0000u);
    return r;
}

// async global->LDS, 16 B per lane; LDS dest = wave-uniform base + lane*16
__device__ __forceinline__ void gload16(const void* g, void* l) {
    __builtin_amdgcn_global_load_lds(
        (const __attribute__((address_space(1))) void*)(uintptr_t)(g),
        (__attribute__((address_space(3))) void*)(uintptr_t)(l), 16, 0, 0);
}

// ---------------- prologue: qpq = bf16(query+qpos) + weight transposes (fp32->bf16)
// + (last block) ss int32->fp32 and concatenated off/aw bias vectors ----------------
struct TDesc { const float* src; ushort_t* dst; int K; int N; };
struct TAll  { TDesc t[10]; };

#define QC4   (QC / 4)        // 1,638,400
#define TRANS_TOTAL 860160
#define PRO_TOTAL (QC4 + TRANS_TOTAL)   // 2,498,560 (multiple of 256)

__global__ __launch_bounds__(256) void prologue_kernel(
    const float* __restrict__ query, const float* __restrict__ qpos,
    ushort_t* __restrict__ qpq, TAll td,
    const int* __restrict__ ss, float* __restrict__ out_ss,
    const float* __restrict__ sa_off_b, const float* __restrict__ sa_aw_b,
    const float* __restrict__ ca_off_b, const float* __restrict__ ca_aw_b,
    float* __restrict__ cb_sa, float* __restrict__ cb_ca)
{
    int i = blockIdx.x * 256 + threadIdx.x;
    if (i >= PRO_TOTAL) {
        int j = i - PRO_TOTAL;
        if (j < 4)   out_ss[j] = (float)ss[j];
        if (j < 96)  cb_sa[j] = (j < 64) ? sa_off_b[j] : sa_aw_b[j - 64];
        if (j < 192) cb_ca[j] = (j < 128) ? ca_off_b[j] : ca_aw_b[j - 128];
        return;
    }
    if (i < QC4) {
        float4 qv = ((const float4*)query)[i];
        float4 pv = ((const float4*)qpos)[i];
        uint2 o;
        o.x = pack2(qv.x + pv.x, qv.y + pv.y);
        o.y = pack2(qv.z + pv.z, qv.w + pv.w);
        ((uint2*)qpq)[i] = o;
        return;
    }
    i -= QC4;
    #pragma unroll 1
    for (int m = 0; m < 10; m++) {
        int sz = td.t[m].K * td.t[m].N;
        if (i < sz) {
            int N = td.t[m].N, K = td.t[m].K;
            int k = i / N, n = i - k * N;
            td.t[m].dst[(size_t)n * K + k] = f2b(td.t[m].src[i]);
            return;
        }
        i -= sz;
    }
}

// ---------------- LDS-staged MFMA GEMM (m97 structure, BK=64 as 2x32 sub-stages) ----------------
// C = A[M,K] @ B[K,N] + bias (+res) (+relu).  Bt = B^T [N,K] bf16.
// Tile BM x 128, 4 waves as 2x2; wave tile (BM/2) x 64.
// AF32: A staged as raw fp32, packed to bf16 on LDS read.
// RESM: 0 none, 1 bf16 residual, 2 fp32 residual.
// VOUT: write head-major value layout [(col>>5)*M + row][32].
template<int BM, bool RELU, int RESM, bool AF32, bool VOUT>
__global__ __launch_bounds__(256) void gemm_lds(
    const ushort_t* __restrict__ A16, const float* __restrict__ A32,
    const ushort_t* __restrict__ Bt, const float* __restrict__ bias,
    const ushort_t* __restrict__ res16, const float* __restrict__ res32,
    ushort_t* __restrict__ Cout, int M, int N, int K)
{
    constexpr int WM = BM / 2;                      // wave tile rows
    constexpr int MR = WM / 16;                     // A frags per wave
    constexpr int ASUB = BM * 32 * (AF32 ? 4 : 2);  // bytes per 32-col A sub-tile
    constexpr int BSUB = 128 * 32 * 2;              // bytes per 32-col B sub-tile
    __shared__ __align__(16) char smem[2 * ASUB + 2 * BSUB];
    char* lA = smem;                                // [2][BM][32] (bf16 or fp32)
    char* lB = smem + 2 * ASUB;                     // [2][128][32] bf16

    const int lane = threadIdx.x & 63;
    const int wave = threadIdx.x >> 6;
    const int wm = wave >> 1, wn = wave & 1;
    const int m0 = blockIdx.x * BM;
    const int n0 = blockIdx.y * 128;
    const int r = lane & 15, quad = lane >> 4;

    f32x4 acc[MR][4];
    #pragma unroll
    for (int i = 0; i < MR; i++)
        #pragma unroll
        for (int j = 0; j < 4; j++) acc[i][j] = (f32x4){0.f, 0.f, 0.f, 0.f};

    for (int k0 = 0; k0 < K; k0 += 64) {
        // ---- stage B: 2 sub-tiles of [128][32] bf16 (64-B rows) ----
        #pragma unroll
        for (int s = 0; s < 2; s++)
            #pragma unroll
            for (int t = 0; t < 2; t++) {
                int row = wave * 32 + t * 16;
                gload16(Bt + (size_t)(n0 + row + (lane >> 2)) * K + k0 + s * 32 + (lane & 3) * 8,
                        lB + s * BSUB + row * 64);
            }
        // ---- stage A: 2 sub-tiles ----
        if (AF32) {
            #pragma unroll
            for (int s = 0; s < 2; s++)
                #pragma unroll
                for (int t = 0; t < BM / 32; t++) {
                    int row = wave * (BM / 4) + t * 8;
                    gload16(A32 + (size_t)(m0 + row + (lane >> 3)) * K + k0 + s * 32 + (lane & 7) * 4,
                            lA + s * ASUB + row * 128);
                }
        } else {
            #pragma unroll
            for (int s = 0; s < 2; s++)
                #pragma unroll
                for (int t = 0; t < BM / 64; t++) {
                    int row = wave * (BM / 4) + t * 16;
                    gload16(A16 + (size_t)(m0 + row + (lane >> 2)) * K + k0 + s * 32 + (lane & 3) * 8,
                            lA + s * ASUB + row * 64);
                }
        }
        __syncthreads();   // compiler emits vmcnt(0) drain before the barrier

        short8 af[2][MR], bf[2][4];
        #pragma unroll
        for (int s = 0; s < 2; s++) {
            #pragma unroll
            for (int i = 0; i < MR; i++) {
                int row = wm * WM + i * 16 + r;
                if (AF32) {
                    const float* p = (const float*)(lA + s * ASUB) + row * 32 + quad * 8;
                    float4 u = *(const float4*)p;
                    float4 v = *(const float4*)(p + 4);
                    af[s][i] = pack8(u, v);
                } else {
                    af[s][i] = *(const short8*)((const ushort_t*)(lA + s * ASUB) + row * 32 + quad * 8);
                }
            }
            #pragma unroll
            for (int j = 0; j < 4; j++) {
                int row = wn * 64 + j * 16 + r;
                bf[s][j] = *(const short8*)((const ushort_t*)(lB + s * BSUB) + row * 32 + quad * 8);
            }
        }
        #pragma unroll
        for (int s = 0; s < 2; s++)
            #pragma unroll
            for (int i = 0; i < MR; i++)
                #pragma unroll
                for (int j = 0; j < 4; j++)
                    acc[i][j] = __builtin_amdgcn_mfma_f32_16x16x32_bf16(af[s][i], bf[s][j], acc[i][j], 0, 0, 0);
        __syncthreads();   // protect LDS before next-iteration stage
    }

    float bv[4];
    #pragma unroll
    for (int j = 0; j < 4; j++) bv[j] = bias[n0 + wn * 64 + j * 16 + r];

    #pragma unroll
    for (int i = 0; i < MR; i++) {
        int row = m0 + wm * WM + i * 16 + quad * 4;
        #pragma unroll
        for (int j = 0; j < 4; j++) {
            int col = n0 + wn * 64 + j * 16 + r;
            #pragma unroll
            for (int t = 0; t < 4; t++) {
                float v = acc[i][j][t] + bv[j];
                if (RESM == 1) v += b2f(res16[(size_t)(row + t) * N + col]);
                if (RESM == 2) v += res32[(size_t)(row + t) * N + col];
                if (RELU) v = fmaxf(v, 0.f);
                if (VOUT) {
                    Cout[((size_t)(col >> 5) * (size_t)M + (size_t)(row + t)) * HD_ + (col & 31)] = f2b(v);
                } else {
                    Cout[(size_t)(row + t) * N + col] = f2b(v);
                }
            }
        }
    }
}

// ---------------- LDS-staged GEMM + fused LayerNorm (N=256, BM=32, 4 waves split cols) ----------------
// y16 = LN(A@B + bias + res) ; optional y2 = bf16(LN_out + qpos).
// Each block owns 32 complete rows -> LN feasible: per-thread partials over its
// 4 cols x 8 rows -> 16-lane butterfly (quad group) -> LDS cross-wave reduce.
// RESM: 1 bf16 residual, 2 fp32 residual.
template<int RESM, bool Y2>
__global__ __launch_bounds__(256) void gemm_ln(
    const ushort_t* __restrict__ A16,
    const ushort_t* __restrict__ Bt, const float* __restrict__ bias,
    const ushort_t* __restrict__ res16, const float* __restrict__ res32,
    const float* __restrict__ lng, const float* __restrict__ lnb,
    ushort_t* __restrict__ y16,
    const float* __restrict__ qpos, ushort_t* __restrict__ y2,
    int M, int K)
{
    constexpr int ASUB = 32 * 32 * 2;    // 2 KB per 32-col A sub-tile
    constexpr int BSUB = 256 * 32 * 2;   // 16 KB per 32-col B sub-tile
    __shared__ __align__(16) char smem[2 * ASUB + 2 * BSUB];   // 36 KB
    char* lA = smem;
    char* lB = smem + 2 * ASUB;

    const int lane = threadIdx.x & 63;
    const int wave = threadIdx.x >> 6;   // wn: column quarter
    const int m0 = blockIdx.x * 32;
    const int r = lane & 15, quad = lane >> 4;

    f32x4 acc[2][4];
    #pragma unroll
    for (int i = 0; i < 2; i++)
        #pragma unroll
        for (int j = 0; j < 4; j++) acc[i][j] = (f32x4){0.f, 0.f, 0.f, 0.f};

    for (int k0 = 0; k0 < K; k0 += 64) {
        // ---- stage A: [2][32][32] bf16 = 4 KB -> 1 inst/wave ----
        {
            int s = wave >> 1;
            int row = (wave & 1) * 16 + (lane >> 2);
            gload16(A16 + (size_t)(m0 + row) * K + k0 + s * 32 + (lane & 3) * 8,
                    lA + s * ASUB + (wave & 1) * 1024);
        }
        // ---- stage B: [2][256][32] bf16 = 32 KB -> 8 insts/wave ----
        #pragma unroll
        for (int s = 0; s < 2; s++)
            #pragma unroll
            for (int t = 0; t < 4; t++) {
                int row0 = wave * 64 + t * 16;
                gload16(Bt + (size_t)(row0 + (lane >> 2)) * K + k0 + s * 32 + (lane & 3) * 8,
                        lB + s * BSUB + row0 * 64);
            }
        __syncthreads();

        short8 af[2][2], bf[2][4];
        #pragma unroll
        for (int s = 0; s < 2; s++) {
            #pragma unroll
            for (int i = 0; i < 2; i++) {
                int row = i * 16 + r;
                af[s][i] = *(const short8*)((const ushort_t*)(lA + s * ASUB) + row * 32 + quad * 8);
            }
            #pragma unroll
            for (int j = 0; j < 4; j++) {
                int row = wave * 64 + j * 16 + r;
                bf[s][j] = *(const short8*)((const ushort_t*)(lB + s * BSUB) + row * 32 + quad * 8);
            }
        }
        #pragma unroll
        for (int s = 0; s < 2; s++)
            #pragma unroll
            for (int i = 0; i < 2; i++)
                #pragma unroll
                for (int j = 0; j < 4; j++)
                    acc[i][j] = __builtin_amdgcn_mfma_f32_16x16x32_bf16(af[s][i], bf[s][j], acc[i][j], 0, 0, 0);
        __syncthreads();
    }

    // ---- epilogue: bias + residual, per-row partial sums ----
    float bv[4];
    #pragma unroll
    for (int j = 0; j < 4; j++) bv[j] = bias[wave * 64 + j * 16 + r];

    float rs[2][4], rq[2][4];
    #pragma unroll
    for (int i = 0; i < 2; i++)
        #pragma unroll
        for (int t = 0; t < 4; t++) { rs[i][t] = 0.f; rq[i][t] = 0.f; }

    #pragma unroll
    for (int i = 0; i < 2; i++)
        #pragma unroll
        for (int j = 0; j < 4; j++) {
            int col = wave * 64 + j * 16 + r;
            #pragma unroll
            for (int t = 0; t < 4; t++) {
                int row = m0 + i * 16 + quad * 4 + t;
                float v = acc[i][j][t] + bv[j];
                if (RESM == 1) v += b2f(res16[(size_t)row * C_ + col]);
                if (RESM == 2) v += res32[(size_t)row * C_ + col];
                acc[i][j][t] = v;
                rs[i][t] += v; rq[i][t] += v * v;
            }
        }

    // 16-lane butterfly within quad group (rows identical across r)
    #pragma unroll
    for (int m = 1; m < 16; m <<= 1)
        #pragma unroll
        for (int i = 0; i < 2; i++)
            #pragma unroll
            for (int t = 0; t < 4; t++) {
                rs[i][t] += __shfl_xor(rs[i][t], m, 64);
                rq[i][t] += __shfl_xor(rq[i][t], m, 64);
            }

    // cross-wave reduce via LDS (tiles dead after final loop barrier)
    float2* red = (float2*)smem;        // [32 rows][4 waves]
    if (r == 0) {
        #pragma unroll
        for (int i = 0; i < 2; i++)
            #pragma unroll
            for (int t = 0; t < 4; t++) {
                int lr = i * 16 + quad * 4 + t;
                red[lr * 4 + wave] = make_float2(rs[i][t], rq[i][t]);
            }
    }
    __syncthreads();

    float mn[2][4], ri[2][4];
    #pragma unroll
    for (int i = 0; i < 2; i++)
        #pragma unroll
        for (int t = 0; t < 4; t++) {
            int lr = i * 16 + quad * 4 + t;
            float s = 0.f, sq = 0.f;
            #pragma unroll
            for (int w = 0; w < 4; w++) { float2 p = red[lr * 4 + w]; s += p.x; sq += p.y; }
            float mean = s * (1.f / 256.f);
            float var  = sq * (1.f / 256.f) - mean * mean;
            mn[i][t] = mean;
            ri[i][t] = rsqrtf(fmaxf(var, 0.f) + 1e-5f);
        }

    float gv[4], bb[4];
    #pragma unroll
    for (int j = 0; j < 4; j++) {
        int col = wave * 64 + j * 16 + r;
        gv[j] = lng[col]; bb[j] = lnb[col];
    }

    #pragma unroll
    for (int i = 0; i < 2; i++)
        #pragma unroll
        for (int j = 0; j < 4; j++) {
            int col = wave * 64 + j * 16 + r;
            #pragma unroll
            for (int t = 0; t < 4; t++) {
                int row = m0 + i * 16 + quad * 4 + t;
                float vn = (acc[i][j][t] - mn[i][t]) * ri[i][t] * gv[j] + bb[j];
                y16[(size_t)row * C_ + col] = f2b(vn);
                if (Y2) y2[(size_t)row * C_ + col] = f2b(vn + qpos[(size_t)row * C_ + col]);
            }
        }
}

// ---------------- reg-direct MFMA GEMM (small-N: fused off+aw projections) ----------------
template<int WN, bool RELU, int RESM>
__global__ __launch_bounds__(256) void gemm_bf16(
    const ushort_t* __restrict__ A16,
    const ushort_t* __restrict__ Bt, const float* __restrict__ bias,
    ushort_t* __restrict__ Cout, int M, int N, int K)
{
    const int lane = threadIdx.x & 63;
    const int wave = threadIdx.x >> 6;
    const int m0 = blockIdx.x * 256 + wave * 64;
    const int n0 = blockIdx.y * (16 * WN);
    const int r = lane & 15, quad = lane >> 4;

    f32x4 acc[4][WN];
    #pragma unroll
    for (int i = 0; i < 4; i++)
        #pragma unroll
        for (int j = 0; j < WN; j++) acc[i][j] = (f32x4){0.f, 0.f, 0.f, 0.f};

    const ushort_t* Ab16 = A16 + (size_t)(m0 + r) * K + quad * 8;
    const ushort_t* Bbase = Bt + (size_t)(n0 + r) * K + quad * 8;

    for (int k0 = 0; k0 < K; k0 += 64) {
        short8 af0[4], af1[4], b0[WN], b1[WN];
        #pragma unroll
        for (int i = 0; i < 4; i++) {
            af0[i] = *(const short8*)(Ab16 + (size_t)i * 16 * K + k0);
            af1[i] = *(const short8*)(Ab16 + (size_t)i * 16 * K + k0 + 32);
        }
        #pragma unroll
        for (int j = 0; j < WN; j++) {
            b0[j] = *(const short8*)(Bbase + (size_t)j * 16 * K + k0);
            b1[j] = *(const short8*)(Bbase + (size_t)j * 16 * K + k0 + 32);
        }
        #pragma unroll
        for (int i = 0; i < 4; i++)
            #pragma unroll
            for (int j = 0; j < WN; j++)
                acc[i][j] = __builtin_amdgcn_mfma_f32_16x16x32_bf16(af0[i], b0[j], acc[i][j], 0, 0, 0);
        #pragma unroll
        for (int i = 0; i < 4; i++)
            #pragma unroll
            for (int j = 0; j < WN; j++)
                acc[i][j] = __builtin_amdgcn_mfma_f32_16x16x32_bf16(af1[i], b1[j], acc[i][j], 0, 0, 0);
    }

    float bv[WN];
    #pragma unroll
    for (int j = 0; j < WN; j++) bv[j] = bias[n0 + j * 16 + r];

    #pragma unroll
    for (int i = 0; i < 4; i++) {
        int row = m0 + i * 16 + quad * 4;
        #pragma unroll
        for (int j = 0; j < WN; j++) {
            int col = n0 + j * 16 + r;
            #pragma unroll
            for (int t = 0; t < 4; t++) {
                float v = acc[i][j][t] + bv[j];
                if (RELU) v = fmaxf(v, 0.f);
                Cout[(size_t)(row + t) * N + col] = f2b(v);
            }
        }
    }
}

// ---------------- fused softmax + bilinear sampling (+ optional passthrough copy) ----------------
template<int L>
__global__ __launch_bounds__(256) void sample_kernel(
    const ushort_t* __restrict__ v,    // head-major projected value (bf16)
    const ushort_t* __restrict__ cb,   // [Q, NH*L*NP*3] combined off+aw (bf16)
    const float*    __restrict__ ref,  // [Q, LC, 2] fp32
    ushort_t* __restrict__ outp,       // [Q, C] bf16
    const float4* __restrict__ cpsrc, float4* __restrict__ cpdst, int cpn)
{
    const int t   = blockIdx.x * 256 + threadIdx.x;
    const int g   = t >> 3;            // (q,h) group
    const int sub = t & 7;             // 4-channel slice within head
    const int q   = g >> 3;
    const int h   = g & 7;
    const int P   = L * NP_;
    const int STR = NH_ * P * 3;       // 96 (L=1) or 192 (L=2)

    // ---- softmax over P logits ----
    float w[2 * NP_];
    {
        union { uint4 q4; uint2 q2; ushort_t u[8]; } ab;
        const ushort_t* awp = cb + (size_t)q * STR + NH_ * P * 2 + h * P;
        if (L == 2) ab.q4 = *(const uint4*)awp;
        else        ab.q2 = *(const uint2*)awp;
        float mx = -1e30f;
        #pragma unroll
        for (int i = 0; i < P; i++) { w[i] = b2f(ab.u[i]); mx = fmaxf(mx, w[i]); }
        float s = 0.f;
        #pragma unroll
        for (int i = 0; i < P; i++) { w[i] = __expf(w[i] - mx); s += w[i]; }
        float inv = 1.f / s;
        #pragma unroll
        for (int i = 0; i < P; i++) w[i] *= inv;
    }

    // ---- offsets ----
    float offx[2 * NP_], offy[2 * NP_];
    {
        union { uint4 q4[2]; ushort_t u[16]; } ob;
        const ushort_t* offp = cb + (size_t)q * STR + h * (P * 2);
        ob.q4[0] = *(const uint4*)offp;
        if (L == 2) ob.q4[1] = *(const uint4*)(offp + 8);
        #pragma unroll
        for (int i = 0; i < P; i++) { offx[i] = b2f(ob.u[2 * i]); offy[i] = b2f(ob.u[2 * i + 1]); }
    }

    const ushort_t* vh = v + ((size_t)(h * L) * Q_) * HD_ + sub * 4;
    float4 acc = {0.f, 0.f, 0.f, 0.f};

    #pragma unroll
    for (int l = 0; l < L; l++) {
        float rx = ref[((size_t)q * LC_ + l) * 2 + 0] * (float)HW_ - 0.5f;
        float ry = ref[((size_t)q * LC_ + l) * 2 + 1] * (float)HW_ - 0.5f;
        const ushort_t* vl = vh + (size_t)l * ((size_t)Q_ * HD_);
        #pragma unroll
        for (int p = 0; p < NP_; p++) {
            const int ip = l * NP_ + p;
            float x = rx + offx[ip];
            float y = ry + offy[ip];
            x = fminf(fmaxf(x, -1e4f), 1e4f);
            y = fminf(fmaxf(y, -1e4f), 1e4f);
            float xf = floorf(x), yf = floorf(y);
            float tx = x - xf, ty = y - yf;
            int x0 = (int)xf, y0 = (int)yf;
            int x1 = x0 + 1, y1 = y0 + 1;
            int xc0 = min(max(x0, 0), HW_ - 1), xc1 = min(max(x1, 0), HW_ - 1);
            int yc0 = min(max(y0, 0), HW_ - 1), yc1 = min(max(y1, 0), HW_ - 1);
            bool vx0 = (unsigned)x0 < (unsigned)HW_, vx1 = (unsigned)x1 < (unsigned)HW_;
            bool vy0 = (unsigned)y0 < (unsigned)HW_, vy1 = (unsigned)y1 < (unsigned)HW_;

            float aww = w[ip];
            float w00 = (1.f - tx) * (1.f - ty) * aww;
            float w10 = tx * (1.f - ty) * aww;
            float w01 = (1.f - tx) * ty * aww;
            float w11 = tx * ty * aww;
            w00 = (vx0 & vy0) ? w00 : 0.f;
            w10 = (vx1 & vy0) ? w10 : 0.f;
            w01 = (vx0 & vy1) ? w01 : 0.f;
            w11 = (vx1 & vy1) ? w11 : 0.f;

            int r0 = yc0 * HW_, r1 = yc1 * HW_;
            uint2 u00 = *(const uint2*)(vl + (size_t)(r0 + xc0) * HD_);
            uint2 u10 = *(const uint2*)(vl + (size_t)(r0 + xc1) * HD_);
            uint2 u01 = *(const uint2*)(vl + (size_t)(r1 + xc0) * HD_);
            uint2 u11 = *(const uint2*)(vl + (size_t)(r1 + xc1) * HD_);
            float4 c00 = unpk4(u00), c10 = unpk4(u10), c01 = unpk4(u01), c11 = unpk4(u11);

            acc.x += c00.x * w00 + c10.x * w10 + c01.x * w01 + c11.x * w11;
            acc.y += c00.y * w00 + c10.y * w10 + c01.y * w01 + c11.y * w11;
            acc.z += c00.z * w00 + c10.z * w10 + c01.z * w01 + c11.z * w11;
            acc.w += c00.w * w00 + c10.w * w10 + c01.w * w01 + c11.w * w11;
        }
    }

    uint2 o;
    o.x = pack2(acc.x, acc.y);
    o.y = pack2(acc.z, acc.w);
    *(uint2*)(outp + (size_t)q * C_ + h * HD_ + sub * 4) = o;

    // ---- folded passthrough copy (grid-stride float4) ----
    if (cpdst) {
        const int nt = gridDim.x * 256;
        for (int i = t; i < cpn; i += nt) cpdst[i] = cpsrc[i];
    }
}

// ---------------- LayerNorm (wave per row of 256) -- used only for LN3 ----------------
template<bool OUT32>
__global__ __launch_bounds__(256) void ln_kernel(
    const ushort_t* __restrict__ x, const float* __restrict__ g,
    const float* __restrict__ b, ushort_t* __restrict__ y16,
    float* __restrict__ y32,
    const float* __restrict__ qpos, ushort_t* __restrict__ y2,
    const float4* __restrict__ cpsrc, float4* __restrict__ cpdst)
{
    const int lane = threadIdx.x & 63;
    const int wave = threadIdx.x >> 6;
    const size_t row = (size_t)blockIdx.x * 4 + wave;
    const size_t base = row * C_ + lane * 4;

    uint2 xv = *(const uint2*)(x + base);
    float f0 = b2f((ushort_t)(xv.x & 0xFFFF)), f1 = b2f((ushort_t)(xv.x >> 16));
    float f2 = b2f((ushort_t)(xv.y & 0xFFFF)), f3 = b2f((ushort_t)(xv.y >> 16));
    float s  = f0 + f1 + f2 + f3;
    float sq = f0 * f0 + f1 * f1 + f2 * f2 + f3 * f3;
    #pragma unroll
    for (int m = 1; m < 64; m <<= 1) { s += __shfl_xor(s, m, 64); sq += __shfl_xor(sq, m, 64); }
    float mean = s * (1.f / 256.f);
    float var  = sq * (1.f / 256.f) - mean * mean;
    float rinv = rsqrtf(fmaxf(var, 0.f) + 1e-5f);

    float4 gv = *(const float4*)(g + lane * 4);
    float4 bv = *(const float4*)(b + lane * 4);
    float o0 = (f0 - mean) * rinv * gv.x + bv.x;
    float o1 = (f1 - mean) * rinv * gv.y + bv.y;
    float o2 = (f2 - mean) * rinv * gv.z + bv.z;
    float o3 = (f3 - mean) * rinv * gv.w + bv.w;

    if (OUT32) {
        float4 o; o.x = o0; o.y = o1; o.z = o2; o.w = o3;
        *(float4*)(y32 + base) = o;
    } else {
        uint2 ov; ov.x = pack2(o0, o1); ov.y = pack2(o2, o3);
        *(uint2*)(y16 + base) = ov;
    }

    if (y2) {
        float4 pv = *(const float4*)(qpos + base);
        uint2 o2v;
        o2v.x = pack2(o0 + pv.x, o1 + pv.y);
        o2v.y = pack2(o2 + pv.z, o3 + pv.w);
        *(uint2*)(y2 + base) = o2v;
    }

    if (cpdst) {
        int tid = blockIdx.x * 256 + threadIdx.x;
        cpdst[tid] = cpsrc[tid];
    }
}

// ---------------- host ----------------
extern "C" void kernel_launch(void* const* d_in, const int* in_sizes, int n_in,
                              void* d_out, int out_size, void* d_ws, size_t ws_size,
                              hipStream_t stream)
{
    const float* query = (const float*)d_in[0];
    const float* qpos  = (const float*)d_in[1];
    const float* value = (const float*)d_in[2];
    const float* ref   = (const float*)d_in[3];
    const int*   ss    = (const int*)d_in[4];
    const float* sa_off_w = (const float*)d_in[5];
    const float* sa_off_b = (const float*)d_in[6];
    const float* sa_aw_w  = (const float*)d_in[7];
    const float* sa_aw_b  = (const float*)d_in[8];
    const float* sa_vp_w  = (const float*)d_in[9];
    const float* sa_vp_b  = (const float*)d_in[10];
    const float* sa_op_w  = (const float*)d_in[11];
    const float* sa_op_b  = (const float*)d_in[12];
    const float* ca_off_w = (const float*)d_in[13];
    const float* ca_off_b = (const float*)d_in[14];
    const float* ca_aw_w  = (const float*)d_in[15];
    const float* ca_aw_b  = (const float*)d_in[16];
    const float* ca_vp_w  = (const float*)d_in[17];
    const float* ca_vp_b  = (const float*)d_in[18];
    const float* ca_op_w  = (const float*)d_in[19];
    const float* ca_op_b  = (const float*)d_in[20];
    const float* ffn_w1   = (const float*)d_in[21];
    const float* ffn_b1   = (const float*)d_in[22];
    const float* ffn_w2   = (const float*)d_in[23];
    const float* ffn_b2   = (const float*)d_in[24];
    const float* ln1_g = (const float*)d_in[25];
    const float* ln1_b = (const float*)d_in[26];
    const float* ln2_g = (const float*)d_in[27];
    const float* ln2_b = (const float*)d_in[28];
    const float* ln3_g = (const float*)d_in[29];
    const float* ln3_b = (const float*)d_in[30];

    // ---- final output layout (fp32) ----
    float* outf    = (float*)d_out;
    float* out_q   = outf;                            // [Q,C]   bytes [0, 26.2M)
    float* out_qp  = outf + QC;                       // [Q,C]   bytes [26.2M, 52.4M)
    float* out_val = outf + 2 * (size_t)QC;           // [2Q,C]  bytes [52.4M, 104.9M)
    float* out_ref = outf + 4 * (size_t)QC;           // [Q,LC,2]
    float* out_ss  = outf + 4 * (size_t)QC + REFN;    // [4]

    // ---- d_out doubles as bf16 body scratch; scratch in bytes [0, 52.4M) ----
    ushort_t* dsc    = (ushort_t*)d_out;
    ushort_t* vbuf   = dsc;                           // 2QC bf16 (head-major value)
    ushort_t* cqa    = dsc + 3 * (size_t)QC;          // Q*192 bf16 max (combined off+aw)
    ushort_t* hidden = dsc;                           // Q*1024 bf16

    // ---- workspace ----
    char* base = (char*)d_ws;
    size_t offbyte = 0;
    auto alloc = [&](size_t elems) -> ushort_t* {
        ushort_t* p = (ushort_t*)(base + offbyte);
        offbyte += ((elems * 2 + 255) / 256) * 256;
        return p;
    };
    ushort_t* wt_sa_off = alloc(256 * 64);
    ushort_t* wt_sa_aw  = alloc(256 * 32);
    ushort_t* wt_sa_vp  = alloc(256 * 256);
    ushort_t* wt_sa_op  = alloc(256 * 256);
    ushort_t* wt_ca_off = alloc(256 * 128);
    ushort_t* wt_ca_aw  = alloc(256 * 64);
    ushort_t* wt_ca_vp  = alloc(256 * 256);
    ushort_t* wt_ca_op  = alloc(256 * 256);
    ushort_t* wt_ffn1   = alloc(256 * 1024);
    ushort_t* wt_ffn2   = alloc(1024 * 256);
    ushort_t* qpq  = alloc(QC);     // bf16(q+pos), then bf16(ln1+pos)
    ushort_t* attn = alloc(QC);     // sampled attention out; later q2 (LN2 out)
    ushort_t* q1   = alloc(QC);     // LN1 out; later FFN2 out
    ushort_t* q2   = attn;          // LN2 out overlays dead attn (same-block rows, safe)
    float* cb_sa_b = (float*)alloc(192);
    float* cb_ca_b = (float*)alloc(384);

    TAll td;
    const float* srcs[10] = {sa_off_w, sa_aw_w, sa_vp_w, sa_op_w, ca_off_w,
                             ca_aw_w, ca_vp_w, ca_op_w, ffn_w1, ffn_w2};
    ushort_t* dsts[10] = {wt_sa_off, wt_sa_aw, wt_sa_vp, wt_sa_op, wt_ca_off,
                          wt_ca_aw, wt_ca_vp, wt_ca_op, wt_ffn1, wt_ffn2};
    int Ks[10] = {256, 256, 256, 256, 256, 256, 256, 256, 256, 1024};
    int Ns[10] = {64, 32, 256, 256, 128, 64, 256, 256, 1024, 256};
    for (int m = 0; m < 10; m++) { td.t[m] = {srcs[m], dsts[m], Ks[m], Ns[m]}; }

    // 1. prologue (+1 block: ss->fp32 + concat bias vectors)
    prologue_kernel<<<PRO_TOTAL / 256 + 1, 256, 0, stream>>>(
        query, qpos, qpq, td, ss, out_ss,
        sa_off_b, sa_aw_b, ca_off_b, ca_aw_b, cb_sa_b, cb_ca_b);

    // ---- self-attention (L=1, value = raw fp32 query) ----
    gemm_lds<64, false, 0, true, true><<<dim3(Q_ / 64, 2), 256, 0, stream>>>(
        nullptr, query, wt_sa_vp, sa_vp_b, nullptr, nullptr, vbuf, Q_, 256, 256);
    gemm_bf16<3, false, 0><<<dim3(Q_ / 256, 2), 256, 0, stream>>>(
        qpq, wt_sa_off, cb_sa_b, cqa, Q_, 96, 256);
    sample_kernel<1><<<(Q_ * NH_) / 32, 256, 0, stream>>>(
        vbuf, cqa, ref, attn, (const float4*)ref, (float4*)out_ref, REFN / 4);
    // sa_op + fused LN1 (y16=q1, y2=qpq=bf16(ln1+qpos))
    gemm_ln<2, true><<<Q_ / 32, 256, 0, stream>>>(
        attn, wt_sa_op, sa_op_b, nullptr, query, ln1_g, ln1_b,
        q1, qpos, qpq, Q_, 256);

    // ---- cross-attention (L=2, value = raw fp32 value) ----
    gemm_lds<64, false, 0, true, true><<<dim3(2 * Q_ / 64, 2), 256, 0, stream>>>(
        nullptr, value, wt_ca_vp, ca_vp_b, nullptr, nullptr, vbuf, 2 * Q_, 256, 256);
    gemm_bf16<3, false, 0><<<dim3(Q_ / 256, 4), 256, 0, stream>>>(
        qpq, wt_ca_off, cb_ca_b, cqa, Q_, 192, 256);
    sample_kernel<2><<<(Q_ * NH_) / 32, 256, 0, stream>>>(
        vbuf, cqa, ref, attn, (const float4*)value, (float4*)out_val, VC / 4);
    // ca_op + fused LN2 (y16=q2; q2 overlays attn -- per-block same-row overwrite, safe)
    gemm_ln<1, false><<<Q_ / 32, 256, 0, stream>>>(
        attn, wt_ca_op, ca_op_b, q1, nullptr, ln2_g, ln2_b,
        q2, nullptr, nullptr, Q_, 256);

    // ---- FFN ----
    gemm_lds<128, true, 0, false, false><<<dim3(Q_ / 128, 8), 256, 0, stream>>>(
        q2, nullptr, wt_ffn1, ffn_b1, nullptr, nullptr, hidden, Q_, 1024, 256);
    gemm_lds<64, false, 1, false, false><<<dim3(Q_ / 64, 2), 256, 0, stream>>>(
        hidden, nullptr, wt_ffn2, ffn_b2, q2, nullptr, q1, Q_, 256, 1024);
    // LN3 -> fp32 final output + folded out_qp copy (hidden region dead now)
    ln_kernel<true><<<Q_ / 4, 256, 0, stream>>>(
        q1, ln3_g, ln3_b, nullptr, out_q, nullptr, nullptr,
        (const float4*)qpos, (float4*)out_qp);

    (void)in_sizes; (void)n_in; (void)out_size; (void)ws_size;
}

// Round 13
// 482.523 us; speedup vs baseline: 1.0187x; 1.0187x over previous
//
#include <hip/hip_runtime.h>

// ---------------- problem constants ----------------
#define Q_   25600
#define C_   256
#define NH_  8
#define HD_  32
#define NP_  4
#define LC_  2
#define HW_  160          // H == W == 160

#define QC   (Q_ * C_)            // 6,553,600
#define VC   (2 * QC)             // 13,107,200
#define REFN (Q_ * LC_ * 2)       // 102,400

typedef unsigned short ushort_t;
typedef __attribute__((ext_vector_type(8))) short short8;
typedef __attribute__((ext_vector_type(4))) float f32x4;

// ---------------- bf16 helpers ----------------
__device__ __forceinline__ float b2f(ushort_t u) {
    union { unsigned int u32; float f; } c; c.u32 = ((unsigned int)u) << 16; return c.f;
}
__device__ __forceinline__ ushort_t f2b(float f) {
    union { float f; unsigned int u32; } c; c.f = f;
    unsigned int u = c.u32;
    return (ushort_t)((u + 0x7FFFu + ((u >> 16) & 1u)) >> 16);
}
__device__ __forceinline__ unsigned int pack2(float lo, float hi){
    return (unsigned int)f2b(lo) | ((unsigned int)f2b(hi) << 16);
}
__device__ __forceinline__ short8 pack8(float4 a, float4 b){
    union { short8 s; ushort_t u[8]; } r;
    r.u[0]=f2b(a.x); r.u[1]=f2b(a.y); r.u[2]=f2b(a.z); r.u[3]=f2b(a.w);
    r.u[4]=f2b(b.x); r.u[5]=f2b(b.y); r.u[6]=f2b(b.z); r.u[7]=f2b(b.w);
    return r.s;
}
__device__ __forceinline__ float uasf(unsigned int u){
    union { unsigned int u32; float f; } c; c.u32 = u; return c.f;
}
// unpack 4 bf16 (packed in uint2) -> 4 floats
__device__ __forceinline__ float4 unpk4(uint2 u){
    float4 r;
    r.x = uasf(u.x << 16); r.y = uasf(u.x & 0xFFFF0000u);
    r.z = uasf(u.y << 16); r.w = uasf(u.y & 0xFFFF0000u);
    return r;
}

// async global->LDS, 16 B per lane; LDS dest = wave-uniform base + lane*16
__device__ __forceinline__ void gload16(const void* g, void* l) {
    __builtin_amdgcn_global_load_lds(
        (const __attribute__((address_space(1))) void*)(uintptr_t)(g),
        (__attribute__((address_space(3))) void*)(uintptr_t)(l), 16, 0, 0);
}

// ---------------- prologue: qpq = bf16(query+qpos) + weight transposes (fp32->bf16)
// + (last block) ss int32->fp32 and concatenated off/aw bias vectors ----------------
struct TDesc { const float* src; ushort_t* dst; int K; int N; };
struct TAll  { TDesc t[10]; };

#define QC4   (QC / 4)        // 1,638,400
#define TRANS_TOTAL 860160
#define PRO_TOTAL (QC4 + TRANS_TOTAL)   // 2,498,560 (multiple of 256)

__global__ __launch_bounds__(256) void prologue_kernel(
    const float* __restrict__ query, const float* __restrict__ qpos,
    ushort_t* __restrict__ qpq, TAll td,
    const int* __restrict__ ss, float* __restrict__ out_ss,
    const float* __restrict__ sa_off_b, const float* __restrict__ sa_aw_b,
    const float* __restrict__ ca_off_b, const float* __restrict__ ca_aw_b,
    float* __restrict__ cb_sa, float* __restrict__ cb_ca)
{
    int i = blockIdx.x * 256 + threadIdx.x;
    if (i >= PRO_TOTAL) {
        int j = i - PRO_TOTAL;
        if (j < 4)   out_ss[j] = (float)ss[j];
        if (j < 96)  cb_sa[j] = (j < 64) ? sa_off_b[j] : sa_aw_b[j - 64];
        if (j < 192) cb_ca[j] = (j < 128) ? ca_off_b[j] : ca_aw_b[j - 128];
        return;
    }
    if (i < QC4) {
        float4 qv = ((const float4*)query)[i];
        float4 pv = ((const float4*)qpos)[i];
        uint2 o;
        o.x = pack2(qv.x + pv.x, qv.y + pv.y);
        o.y = pack2(qv.z + pv.z, qv.w + pv.w);
        ((uint2*)qpq)[i] = o;
        return;
    }
    i -= QC4;
    #pragma unroll 1
    for (int m = 0; m < 10; m++) {
        int sz = td.t[m].K * td.t[m].N;
        if (i < sz) {
            int N = td.t[m].N, K = td.t[m].K;
            int k = i / N, n = i - k * N;
            td.t[m].dst[(size_t)n * K + k] = f2b(td.t[m].src[i]);
            return;
        }
        i -= sz;
    }
}

// ---------------- LDS-staged MFMA GEMM (m97 structure, BK=64 as 2x32 sub-stages) ----------------
// C = A[M,K] @ B[K,N] + bias (+res) (+relu).  Bt = B^T [N,K] bf16.
// Tile BM x 128, 4 waves as 2x2; wave tile (BM/2) x 64.
// AF32: A staged as raw fp32, packed to bf16 on LDS read.
// RESM: 0 none, 1 bf16 residual, 2 fp32 residual.
// VOUT: write head-major value layout [(col>>5)*M + row][32].
// cpsrc/cpdst: grid-stride float4 passthrough copy folded into this
// latency-bound kernel's idle HBM bandwidth.
template<int BM, bool RELU, int RESM, bool AF32, bool VOUT>
__global__ __launch_bounds__(256) void gemm_lds(
    const ushort_t* __restrict__ A16, const float* __restrict__ A32,
    const ushort_t* __restrict__ Bt, const float* __restrict__ bias,
    const ushort_t* __restrict__ res16, const float* __restrict__ res32,
    ushort_t* __restrict__ Cout, int M, int N, int K,
    const float4* __restrict__ cpsrc, float4* __restrict__ cpdst, int cpn)
{
    constexpr int WM = BM / 2;                      // wave tile rows
    constexpr int MR = WM / 16;                     // A frags per wave
    constexpr int ASUB = BM * 32 * (AF32 ? 4 : 2);  // bytes per 32-col A sub-tile
    constexpr int BSUB = 128 * 32 * 2;              // bytes per 32-col B sub-tile
    __shared__ __align__(16) char smem[2 * ASUB + 2 * BSUB];
    char* lA = smem;                                // [2][BM][32] (bf16 or fp32)
    char* lB = smem + 2 * ASUB;                     // [2][128][32] bf16

    const int lane = threadIdx.x & 63;
    const int wave = threadIdx.x >> 6;
    const int wm = wave >> 1, wn = wave & 1;
    const int m0 = blockIdx.x * BM;
    const int n0 = blockIdx.y * 128;
    const int r = lane & 15, quad = lane >> 4;

    f32x4 acc[MR][4];
    #pragma unroll
    for (int i = 0; i < MR; i++)
        #pragma unroll
        for (int j = 0; j < 4; j++) acc[i][j] = (f32x4){0.f, 0.f, 0.f, 0.f};

    for (int k0 = 0; k0 < K; k0 += 64) {
        // ---- stage B: 2 sub-tiles of [128][32] bf16 (64-B rows) ----
        #pragma unroll
        for (int s = 0; s < 2; s++)
            #pragma unroll
            for (int t = 0; t < 2; t++) {
                int row = wave * 32 + t * 16;
                gload16(Bt + (size_t)(n0 + row + (lane >> 2)) * K + k0 + s * 32 + (lane & 3) * 8,
                        lB + s * BSUB + row * 64);
            }
        // ---- stage A: 2 sub-tiles ----
        if (AF32) {
            #pragma unroll
            for (int s = 0; s < 2; s++)
                #pragma unroll
                for (int t = 0; t < BM / 32; t++) {
                    int row = wave * (BM / 4) + t * 8;
                    gload16(A32 + (size_t)(m0 + row + (lane >> 3)) * K + k0 + s * 32 + (lane & 7) * 4,
                            lA + s * ASUB + row * 128);
                }
        } else {
            #pragma unroll
            for (int s = 0; s < 2; s++)
                #pragma unroll
                for (int t = 0; t < BM / 64; t++) {
                    int row = wave * (BM / 4) + t * 16;
                    gload16(A16 + (size_t)(m0 + row + (lane >> 2)) * K + k0 + s * 32 + (lane & 3) * 8,
                            lA + s * ASUB + row * 64);
                }
        }
        __syncthreads();   // compiler emits vmcnt(0) drain before the barrier

        short8 af[2][MR], bf[2][4];
        #pragma unroll
        for (int s = 0; s < 2; s++) {
            #pragma unroll
            for (int i = 0; i < MR; i++) {
                int row = wm * WM + i * 16 + r;
                if (AF32) {
                    const float* p = (const float*)(lA + s * ASUB) + row * 32 + quad * 8;
                    float4 u = *(const float4*)p;
                    float4 v = *(const float4*)(p + 4);
                    af[s][i] = pack8(u, v);
                } else {
                    af[s][i] = *(const short8*)((const ushort_t*)(lA + s * ASUB) + row * 32 + quad * 8);
                }
            }
            #pragma unroll
            for (int j = 0; j < 4; j++) {
                int row = wn * 64 + j * 16 + r;
                bf[s][j] = *(const short8*)((const ushort_t*)(lB + s * BSUB) + row * 32 + quad * 8);
            }
        }
        #pragma unroll
        for (int s = 0; s < 2; s++)
            #pragma unroll
            for (int i = 0; i < MR; i++)
                #pragma unroll
                for (int j = 0; j < 4; j++)
                    acc[i][j] = __builtin_amdgcn_mfma_f32_16x16x32_bf16(af[s][i], bf[s][j], acc[i][j], 0, 0, 0);
        __syncthreads();   // protect LDS before next-iteration stage
    }

    float bv[4];
    #pragma unroll
    for (int j = 0; j < 4; j++) bv[j] = bias[n0 + wn * 64 + j * 16 + r];

    #pragma unroll
    for (int i = 0; i < MR; i++) {
        int row = m0 + wm * WM + i * 16 + quad * 4;
        #pragma unroll
        for (int j = 0; j < 4; j++) {
            int col = n0 + wn * 64 + j * 16 + r;
            #pragma unroll
            for (int t = 0; t < 4; t++) {
                float v = acc[i][j][t] + bv[j];
                if (RESM == 1) v += b2f(res16[(size_t)(row + t) * N + col]);
                if (RESM == 2) v += res32[(size_t)(row + t) * N + col];
                if (RELU) v = fmaxf(v, 0.f);
                if (VOUT) {
                    Cout[((size_t)(col >> 5) * (size_t)M + (size_t)(row + t)) * HD_ + (col & 31)] = f2b(v);
                } else {
                    Cout[(size_t)(row + t) * N + col] = f2b(v);
                }
            }
        }
    }

    // ---- folded passthrough copy (grid-stride float4; targets never scratch) ----
    if (cpdst) {
        int tid = (blockIdx.y * gridDim.x + blockIdx.x) * 256 + threadIdx.x;
        int nt = gridDim.x * gridDim.y * 256;
        for (int i = tid; i < cpn; i += nt) cpdst[i] = cpsrc[i];
    }
}

// ---------------- LDS-staged GEMM + fused LayerNorm (N=256, BM=32, 4 waves split cols) ----------------
// y16 = LN(A@B + bias + res) ; optional y2 = bf16(LN_out + qpos).
// RESM: 1 bf16 residual, 2 fp32 residual.
template<int RESM, bool Y2>
__global__ __launch_bounds__(256) void gemm_ln(
    const ushort_t* __restrict__ A16,
    const ushort_t* __restrict__ Bt, const float* __restrict__ bias,
    const ushort_t* __restrict__ res16, const float* __restrict__ res32,
    const float* __restrict__ lng, const float* __restrict__ lnb,
    ushort_t* __restrict__ y16,
    const float* __restrict__ qpos, ushort_t* __restrict__ y2,
    int M, int K)
{
    constexpr int ASUB = 32 * 32 * 2;    // 2 KB per 32-col A sub-tile
    constexpr int BSUB = 256 * 32 * 2;   // 16 KB per 32-col B sub-tile
    __shared__ __align__(16) char smem[2 * ASUB + 2 * BSUB];   // 36 KB
    char* lA = smem;
    char* lB = smem + 2 * ASUB;

    const int lane = threadIdx.x & 63;
    const int wave = threadIdx.x >> 6;   // column quarter
    const int m0 = blockIdx.x * 32;
    const int r = lane & 15, quad = lane >> 4;

    f32x4 acc[2][4];
    #pragma unroll
    for (int i = 0; i < 2; i++)
        #pragma unroll
        for (int j = 0; j < 4; j++) acc[i][j] = (f32x4){0.f, 0.f, 0.f, 0.f};

    for (int k0 = 0; k0 < K; k0 += 64) {
        {
            int s = wave >> 1;
            int row = (wave & 1) * 16 + (lane >> 2);
            gload16(A16 + (size_t)(m0 + row) * K + k0 + s * 32 + (lane & 3) * 8,
                    lA + s * ASUB + (wave & 1) * 1024);
        }
        #pragma unroll
        for (int s = 0; s < 2; s++)
            #pragma unroll
            for (int t = 0; t < 4; t++) {
                int row0 = wave * 64 + t * 16;
                gload16(Bt + (size_t)(row0 + (lane >> 2)) * K + k0 + s * 32 + (lane & 3) * 8,
                        lB + s * BSUB + row0 * 64);
            }
        __syncthreads();

        short8 af[2][2], bf[2][4];
        #pragma unroll
        for (int s = 0; s < 2; s++) {
            #pragma unroll
            for (int i = 0; i < 2; i++) {
                int row = i * 16 + r;
                af[s][i] = *(const short8*)((const ushort_t*)(lA + s * ASUB) + row * 32 + quad * 8);
            }
            #pragma unroll
            for (int j = 0; j < 4; j++) {
                int row = wave * 64 + j * 16 + r;
                bf[s][j] = *(const short8*)((const ushort_t*)(lB + s * BSUB) + row * 32 + quad * 8);
            }
        }
        #pragma unroll
        for (int s = 0; s < 2; s++)
            #pragma unroll
            for (int i = 0; i < 2; i++)
                #pragma unroll
                for (int j = 0; j < 4; j++)
                    acc[i][j] = __builtin_amdgcn_mfma_f32_16x16x32_bf16(af[s][i], bf[s][j], acc[i][j], 0, 0, 0);
        __syncthreads();
    }

    float bv[4];
    #pragma unroll
    for (int j = 0; j < 4; j++) bv[j] = bias[wave * 64 + j * 16 + r];

    float rs[2][4], rq[2][4];
    #pragma unroll
    for (int i = 0; i < 2; i++)
        #pragma unroll
        for (int t = 0; t < 4; t++) { rs[i][t] = 0.f; rq[i][t] = 0.f; }

    #pragma unroll
    for (int i = 0; i < 2; i++)
        #pragma unroll
        for (int j = 0; j < 4; j++) {
            int col = wave * 64 + j * 16 + r;
            #pragma unroll
            for (int t = 0; t < 4; t++) {
                int row = m0 + i * 16 + quad * 4 + t;
                float v = acc[i][j][t] + bv[j];
                if (RESM == 1) v += b2f(res16[(size_t)row * C_ + col]);
                if (RESM == 2) v += res32[(size_t)row * C_ + col];
                acc[i][j][t] = v;
                rs[i][t] += v; rq[i][t] += v * v;
            }
        }

    #pragma unroll
    for (int m = 1; m < 16; m <<= 1)
        #pragma unroll
        for (int i = 0; i < 2; i++)
            #pragma unroll
            for (int t = 0; t < 4; t++) {
                rs[i][t] += __shfl_xor(rs[i][t], m, 64);
                rq[i][t] += __shfl_xor(rq[i][t], m, 64);
            }

    float2* red = (float2*)smem;        // [32 rows][4 waves]
    if (r == 0) {
        #pragma unroll
        for (int i = 0; i < 2; i++)
            #pragma unroll
            for (int t = 0; t < 4; t++) {
                int lr = i * 16 + quad * 4 + t;
                red[lr * 4 + wave] = make_float2(rs[i][t], rq[i][t]);
            }
    }
    __syncthreads();

    float mn[2][4], ri[2][4];
    #pragma unroll
    for (int i = 0; i < 2; i++)
        #pragma unroll
        for (int t = 0; t < 4; t++) {
            int lr = i * 16 + quad * 4 + t;
            float s = 0.f, sq = 0.f;
            #pragma unroll
            for (int w = 0; w < 4; w++) { float2 p = red[lr * 4 + w]; s += p.x; sq += p.y; }
            float mean = s * (1.f / 256.f);
            float var  = sq * (1.f / 256.f) - mean * mean;
            mn[i][t] = mean;
            ri[i][t] = rsqrtf(fmaxf(var, 0.f) + 1e-5f);
        }

    float gv[4], bb[4];
    #pragma unroll
    for (int j = 0; j < 4; j++) {
        int col = wave * 64 + j * 16 + r;
        gv[j] = lng[col]; bb[j] = lnb[col];
    }

    #pragma unroll
    for (int i = 0; i < 2; i++)
        #pragma unroll
        for (int j = 0; j < 4; j++) {
            int col = wave * 64 + j * 16 + r;
            #pragma unroll
            for (int t = 0; t < 4; t++) {
                int row = m0 + i * 16 + quad * 4 + t;
                float vn = (acc[i][j][t] - mn[i][t]) * ri[i][t] * gv[j] + bb[j];
                y16[(size_t)row * C_ + col] = f2b(vn);
                if (Y2) y2[(size_t)row * C_ + col] = f2b(vn + qpos[(size_t)row * C_ + col]);
            }
        }
}

// ---------------- reg-direct MFMA GEMM (small-N: fused off+aw projections) ----------------
template<int WN, bool RELU, int RESM>
__global__ __launch_bounds__(256) void gemm_bf16(
    const ushort_t* __restrict__ A16,
    const ushort_t* __restrict__ Bt, const float* __restrict__ bias,
    ushort_t* __restrict__ Cout, int M, int N, int K)
{
    const int lane = threadIdx.x & 63;
    const int wave = threadIdx.x >> 6;
    const int m0 = blockIdx.x * 256 + wave * 64;
    const int n0 = blockIdx.y * (16 * WN);
    const int r = lane & 15, quad = lane >> 4;

    f32x4 acc[4][WN];
    #pragma unroll
    for (int i = 0; i < 4; i++)
        #pragma unroll
        for (int j = 0; j < WN; j++) acc[i][j] = (f32x4){0.f, 0.f, 0.f, 0.f};

    const ushort_t* Ab16 = A16 + (size_t)(m0 + r) * K + quad * 8;
    const ushort_t* Bbase = Bt + (size_t)(n0 + r) * K + quad * 8;

    for (int k0 = 0; k0 < K; k0 += 64) {
        short8 af0[4], af1[4], b0[WN], b1[WN];
        #pragma unroll
        for (int i = 0; i < 4; i++) {
            af0[i] = *(const short8*)(Ab16 + (size_t)i * 16 * K + k0);
            af1[i] = *(const short8*)(Ab16 + (size_t)i * 16 * K + k0 + 32);
        }
        #pragma unroll
        for (int j = 0; j < WN; j++) {
            b0[j] = *(const short8*)(Bbase + (size_t)j * 16 * K + k0);
            b1[j] = *(const short8*)(Bbase + (size_t)j * 16 * K + k0 + 32);
        }
        #pragma unroll
        for (int i = 0; i < 4; i++)
            #pragma unroll
            for (int j = 0; j < WN; j++)
                acc[i][j] = __builtin_amdgcn_mfma_f32_16x16x32_bf16(af0[i], b0[j], acc[i][j], 0, 0, 0);
        #pragma unroll
        for (int i = 0; i < 4; i++)
            #pragma unroll
            for (int j = 0; j < WN; j++)
                acc[i][j] = __builtin_amdgcn_mfma_f32_16x16x32_bf16(af1[i], b1[j], acc[i][j], 0, 0, 0);
    }

    float bv[WN];
    #pragma unroll
    for (int j = 0; j < WN; j++) bv[j] = bias[n0 + j * 16 + r];

    #pragma unroll
    for (int i = 0; i < 4; i++) {
        int row = m0 + i * 16 + quad * 4;
        #pragma unroll
        for (int j = 0; j < WN; j++) {
            int col = n0 + j * 16 + r;
            #pragma unroll
            for (int t = 0; t < 4; t++) {
                float v = acc[i][j][t] + bv[j];
                if (RELU) v = fmaxf(v, 0.f);
                Cout[(size_t)(row + t) * N + col] = f2b(v);
            }
        }
    }
}

// ---------------- fused softmax + bilinear sampling (lane-split geometry) ----------------
// v layout: [(h*L + l)*Q + pix][HD]  (head-major, 64 B per pixel record)
// cb: combined [Q][off(NH*P*2) ++ aw(NH*P)] bf16.
// 8 lanes per (q,h) group; each lane owns 4 channels.
// Geometry (coords/weights/addresses) is computed ONCE per point by its owner
// lane and broadcast via __shfl (ds_bpermute = LDS pipe, idle here) -- removes
// the 8x-replicated VALU coordinate math.
template<int L>
__global__ __launch_bounds__(256) void sample_kernel(
    const ushort_t* __restrict__ v,    // head-major projected value (bf16)
    const ushort_t* __restrict__ cb,   // [Q, NH*L*NP*3] combined off+aw (bf16)
    const float*    __restrict__ ref,  // [Q, LC, 2] fp32
    ushort_t* __restrict__ outp)       // [Q, C] bf16
{
    const int t    = blockIdx.x * 256 + threadIdx.x;
    const int lane = threadIdx.x & 63;
    const int g    = t >> 3;           // (q,h) group
    const int sub  = t & 7;            // 4-channel slice within head; also own-point id
    const int q    = g >> 3;
    const int h    = g & 7;
    const int P    = L * NP_;
    const int STR  = NH_ * P * 3;      // 96 (L=1) or 192 (L=2)

    // ---- softmax over P logits (replicated; vectorized bf16 load) ----
    float w[2 * NP_];
    {
        union { uint4 q4; uint2 q2; ushort_t u[8]; } ab;
        const ushort_t* awp = cb + (size_t)q * STR + NH_ * P * 2 + h * P;
        if (L == 2) ab.q4 = *(const uint4*)awp;
        else        ab.q2 = *(const uint2*)awp;
        float mx = -1e30f;
        #pragma unroll
        for (int i = 0; i < P; i++) { w[i] = b2f(ab.u[i]); mx = fmaxf(mx, w[i]); }
        float s = 0.f;
        #pragma unroll
        for (int i = 0; i < P; i++) { w[i] = __expf(w[i] - mx); s += w[i]; }
        float inv = 1.f / s;
        #pragma unroll
        for (int i = 0; i < P; i++) w[i] *= inv;
    }

    // ---- own point geometry (one point per lane; L=1: lanes 4-7 duplicate 0-3) ----
    const int ip = (L == 2) ? sub : (sub & 3);
    float w00, w10, w01, w11;
    int   o00, o10, o01, o11;
    {
        unsigned int op = *(const unsigned int*)(cb + (size_t)q * STR + h * (P * 2) + ip * 2);
        float ox = b2f((ushort_t)(op & 0xFFFF)), oy = b2f((ushort_t)(op >> 16));
        int l = ip >> 2;   // 0 for L=1
        float rx = ref[((size_t)q * LC_ + l) * 2 + 0] * (float)HW_ - 0.5f;
        float ry = ref[((size_t)q * LC_ + l) * 2 + 1] * (float)HW_ - 0.5f;
        float x = fminf(fmaxf(rx + ox, -1e4f), 1e4f);
        float y = fminf(fmaxf(ry + oy, -1e4f), 1e4f);
        float xf = floorf(x), yf = floorf(y);
        float tx = x - xf, ty = y - yf;
        int x0 = (int)xf, y0 = (int)yf;
        int x1 = x0 + 1, y1 = y0 + 1;
        int xc0 = min(max(x0, 0), HW_ - 1), xc1 = min(max(x1, 0), HW_ - 1);
        int yc0 = min(max(y0, 0), HW_ - 1), yc1 = min(max(y1, 0), HW_ - 1);
        bool vx0 = (unsigned)x0 < (unsigned)HW_, vx1 = (unsigned)x1 < (unsigned)HW_;
        bool vy0 = (unsigned)y0 < (unsigned)HW_, vy1 = (unsigned)y1 < (unsigned)HW_;
        float aww = w[ip];
        float ax0 = (1.f - tx) * aww, ax1 = tx * aww;
        w00 = ax0 * (1.f - ty); w10 = ax1 * (1.f - ty);
        w01 = ax0 * ty;         w11 = ax1 * ty;
        w00 = (vx0 & vy0) ? w00 : 0.f;
        w10 = (vx1 & vy0) ? w10 : 0.f;
        w01 = (vx0 & vy1) ? w01 : 0.f;
        w11 = (vx1 & vy1) ? w11 : 0.f;
        int r0 = yc0 * HW_, r1 = yc1 * HW_;
        o00 = (r0 + xc0) * HD_; o10 = (r0 + xc1) * HD_;
        o01 = (r1 + xc0) * HD_; o11 = (r1 + xc1) * HD_;
    }

    const ushort_t* vh = v + ((size_t)(h * L) * Q_) * HD_ + sub * 4;
    const int gbase = lane & ~7;
    float4 acc = {0.f, 0.f, 0.f, 0.f};

    #pragma unroll
    for (int p = 0; p < P; p++) {
        int src = gbase | p;           // owner lane of point p (L=1: p<4)
        float a00 = __shfl(w00, src, 64), a10 = __shfl(w10, src, 64);
        float a01 = __shfl(w01, src, 64), a11 = __shfl(w11, src, 64);
        int   b00 = __shfl(o00, src, 64), b10 = __shfl(o10, src, 64);
        int   b01 = __shfl(o01, src, 64), b11 = __shfl(o11, src, 64);
        const ushort_t* vl = vh + (size_t)(p >> 2) * ((size_t)Q_ * HD_);
        uint2 u00 = *(const uint2*)(vl + b00);
        uint2 u10 = *(const uint2*)(vl + b10);
        uint2 u01 = *(const uint2*)(vl + b01);
        uint2 u11 = *(const uint2*)(vl + b11);
        float4 c00 = unpk4(u00), c10 = unpk4(u10), c01 = unpk4(u01), c11 = unpk4(u11);
        acc.x += c00.x * a00 + c10.x * a10 + c01.x * a01 + c11.x * a11;
        acc.y += c00.y * a00 + c10.y * a10 + c01.y * a01 + c11.y * a11;
        acc.z += c00.z * a00 + c10.z * a10 + c01.z * a01 + c11.z * a11;
        acc.w += c00.w * a00 + c10.w * a10 + c01.w * a01 + c11.w * a11;
    }

    uint2 o;
    o.x = pack2(acc.x, acc.y);
    o.y = pack2(acc.z, acc.w);
    *(uint2*)(outp + (size_t)q * C_ + h * HD_ + sub * 4) = o;
}

// ---------------- LayerNorm (wave per row of 256) -- used only for LN3 ----------------
template<bool OUT32>
__global__ __launch_bounds__(256) void ln_kernel(
    const ushort_t* __restrict__ x, const float* __restrict__ g,
    const float* __restrict__ b, ushort_t* __restrict__ y16,
    float* __restrict__ y32,
    const float* __restrict__ qpos, ushort_t* __restrict__ y2,
    const float4* __restrict__ cpsrc, float4* __restrict__ cpdst)
{
    const int lane = threadIdx.x & 63;
    const int wave = threadIdx.x >> 6;
    const size_t row = (size_t)blockIdx.x * 4 + wave;
    const size_t base = row * C_ + lane * 4;

    uint2 xv = *(const uint2*)(x + base);
    float f0 = b2f((ushort_t)(xv.x & 0xFFFF)), f1 = b2f((ushort_t)(xv.x >> 16));
    float f2 = b2f((ushort_t)(xv.y & 0xFFFF)), f3 = b2f((ushort_t)(xv.y >> 16));
    float s  = f0 + f1 + f2 + f3;
    float sq = f0 * f0 + f1 * f1 + f2 * f2 + f3 * f3;
    #pragma unroll
    for (int m = 1; m < 64; m <<= 1) { s += __shfl_xor(s, m, 64); sq += __shfl_xor(sq, m, 64); }
    float mean = s * (1.f / 256.f);
    float var  = sq * (1.f / 256.f) - mean * mean;
    float rinv = rsqrtf(fmaxf(var, 0.f) + 1e-5f);

    float4 gv = *(const float4*)(g + lane * 4);
    float4 bv = *(const float4*)(b + lane * 4);
    float o0 = (f0 - mean) * rinv * gv.x + bv.x;
    float o1 = (f1 - mean) * rinv * gv.y + bv.y;
    float o2 = (f2 - mean) * rinv * gv.z + bv.z;
    float o3 = (f3 - mean) * rinv * gv.w + bv.w;

    if (OUT32) {
        float4 o; o.x = o0; o.y = o1; o.z = o2; o.w = o3;
        *(float4*)(y32 + base) = o;
    } else {
        uint2 ov; ov.x = pack2(o0, o1); ov.y = pack2(o2, o3);
        *(uint2*)(y16 + base) = ov;
    }

    if (y2) {
        float4 pv = *(const float4*)(qpos + base);
        uint2 o2v;
        o2v.x = pack2(o0 + pv.x, o1 + pv.y);
        o2v.y = pack2(o2 + pv.z, o3 + pv.w);
        *(uint2*)(y2 + base) = o2v;
    }

    if (cpdst) {
        int tid = blockIdx.x * 256 + threadIdx.x;
        cpdst[tid] = cpsrc[tid];
    }
}

// ---------------- host ----------------
extern "C" void kernel_launch(void* const* d_in, const int* in_sizes, int n_in,
                              void* d_out, int out_size, void* d_ws, size_t ws_size,
                              hipStream_t stream)
{
    const float* query = (const float*)d_in[0];
    const float* qpos  = (const float*)d_in[1];
    const float* value = (const float*)d_in[2];
    const float* ref   = (const float*)d_in[3];
    const int*   ss    = (const int*)d_in[4];
    const float* sa_off_w = (const float*)d_in[5];
    const float* sa_off_b = (const float*)d_in[6];
    const float* sa_aw_w  = (const float*)d_in[7];
    const float* sa_aw_b  = (const float*)d_in[8];
    const float* sa_vp_w  = (const float*)d_in[9];
    const float* sa_vp_b  = (const float*)d_in[10];
    const float* sa_op_w  = (const float*)d_in[11];
    const float* sa_op_b  = (const float*)d_in[12];
    const float* ca_off_w = (const float*)d_in[13];
    const float* ca_off_b = (const float*)d_in[14];
    const float* ca_aw_w  = (const float*)d_in[15];
    const float* ca_aw_b  = (const float*)d_in[16];
    const float* ca_vp_w  = (const float*)d_in[17];
    const float* ca_vp_b  = (const float*)d_in[18];
    const float* ca_op_w  = (const float*)d_in[19];
    const float* ca_op_b  = (const float*)d_in[20];
    const float* ffn_w1   = (const float*)d_in[21];
    const float* ffn_b1   = (const float*)d_in[22];
    const float* ffn_w2   = (const float*)d_in[23];
    const float* ffn_b2   = (const float*)d_in[24];
    const float* ln1_g = (const float*)d_in[25];
    const float* ln1_b = (const float*)d_in[26];
    const float* ln2_g = (const float*)d_in[27];
    const float* ln2_b = (const float*)d_in[28];
    const float* ln3_g = (const float*)d_in[29];
    const float* ln3_b = (const float*)d_in[30];

    // ---- final output layout (fp32) ----
    float* outf    = (float*)d_out;
    float* out_q   = outf;                            // [Q,C]   bytes [0, 26.2M)
    float* out_qp  = outf + QC;                       // [Q,C]   bytes [26.2M, 52.4M)
    float* out_val = outf + 2 * (size_t)QC;           // [2Q,C]  bytes [52.4M, 104.9M)
    float* out_ref = outf + 4 * (size_t)QC;           // [Q,LC,2]
    float* out_ss  = outf + 4 * (size_t)QC + REFN;    // [4]

    // ---- d_out doubles as bf16 body scratch; scratch in bytes [0, 52.4M) ----
    // out_val / out_ref / out_ss regions are NEVER scratch -> safe to fill early.
    ushort_t* dsc    = (ushort_t*)d_out;
    ushort_t* vbuf   = dsc;                           // 2QC bf16 (head-major value)
    ushort_t* cqa    = dsc + 3 * (size_t)QC;          // Q*192 bf16 max (combined off+aw)
    ushort_t* hidden = dsc;                           // Q*1024 bf16

    // ---- workspace ----
    char* base = (char*)d_ws;
    size_t offbyte = 0;
    auto alloc = [&](size_t elems) -> ushort_t* {
        ushort_t* p = (ushort_t*)(base + offbyte);
        offbyte += ((elems * 2 + 255) / 256) * 256;
        return p;
    };
    ushort_t* wt_sa_off = alloc(256 * 64);
    ushort_t* wt_sa_aw  = alloc(256 * 32);
    ushort_t* wt_sa_vp  = alloc(256 * 256);
    ushort_t* wt_sa_op  = alloc(256 * 256);
    ushort_t* wt_ca_off = alloc(256 * 128);
    ushort_t* wt_ca_aw  = alloc(256 * 64);
    ushort_t* wt_ca_vp  = alloc(256 * 256);
    ushort_t* wt_ca_op  = alloc(256 * 256);
    ushort_t* wt_ffn1   = alloc(256 * 1024);
    ushort_t* wt_ffn2   = alloc(1024 * 256);
    ushort_t* qpq  = alloc(QC);     // bf16(q+pos), then bf16(ln1+pos)
    ushort_t* attn = alloc(QC);     // sampled attention out; later q2 (LN2 out)
    ushort_t* q1   = alloc(QC);     // LN1 out; later FFN2 out
    ushort_t* q2   = attn;          // LN2 out overlays dead attn (same-block rows, safe)
    float* cb_sa_b = (float*)alloc(192);
    float* cb_ca_b = (float*)alloc(384);

    TAll td;
    const float* srcs[10] = {sa_off_w, sa_aw_w, sa_vp_w, sa_op_w, ca_off_w,
                             ca_aw_w, ca_vp_w, ca_op_w, ffn_w1, ffn_w2};
    ushort_t* dsts[10] = {wt_sa_off, wt_sa_aw, wt_sa_vp, wt_sa_op, wt_ca_off,
                          wt_ca_aw, wt_ca_vp, wt_ca_op, wt_ffn1, wt_ffn2};
    int Ks[10] = {256, 256, 256, 256, 256, 256, 256, 256, 256, 1024};
    int Ns[10] = {64, 32, 256, 256, 128, 64, 256, 256, 1024, 256};
    for (int m = 0; m < 10; m++) { td.t[m] = {srcs[m], dsts[m], Ks[m], Ns[m]}; }

    // 1. prologue (+1 block: ss->fp32 + concat bias vectors)
    prologue_kernel<<<PRO_TOTAL / 256 + 1, 256, 0, stream>>>(
        query, qpos, qpq, td, ss, out_ss,
        sa_off_b, sa_aw_b, ca_off_b, ca_aw_b, cb_sa_b, cb_ca_b);

    // ---- self-attention (L=1, value = raw fp32 query) ----
    // sa_vp + folded out_ref copy (out_ref never scratch)
    gemm_lds<64, false, 0, true, true><<<dim3(Q_ / 64, 2), 256, 0, stream>>>(
        nullptr, query, wt_sa_vp, sa_vp_b, nullptr, nullptr, vbuf, Q_, 256, 256,
        (const float4*)ref, (float4*)out_ref, REFN / 4);
    gemm_bf16<3, false, 0><<<dim3(Q_ / 256, 2), 256, 0, stream>>>(
        qpq, wt_sa_off, cb_sa_b, cqa, Q_, 96, 256);
    sample_kernel<1><<<(Q_ * NH_) / 32, 256, 0, stream>>>(vbuf, cqa, ref, attn);
    // sa_op + fused LN1 (y16=q1, y2=qpq=bf16(ln1+qpos))
    gemm_ln<2, true><<<Q_ / 32, 256, 0, stream>>>(
        attn, wt_sa_op, sa_op_b, nullptr, query, ln1_g, ln1_b,
        q1, qpos, qpq, Q_, 256);

    // ---- cross-attention (L=2, value = raw fp32 value) ----
    // ca_vp + folded out_val copy (out_val never scratch; BW-idle GEMM hides it)
    gemm_lds<64, false, 0, true, true><<<dim3(2 * Q_ / 64, 2), 256, 0, stream>>>(
        nullptr, value, wt_ca_vp, ca_vp_b, nullptr, nullptr, vbuf, 2 * Q_, 256, 256,
        (const float4*)value, (float4*)out_val, VC / 4);
    gemm_bf16<3, false, 0><<<dim3(Q_ / 256, 4), 256, 0, stream>>>(
        qpq, wt_ca_off, cb_ca_b, cqa, Q_, 192, 256);
    sample_kernel<2><<<(Q_ * NH_) / 32, 256, 0, stream>>>(vbuf, cqa, ref, attn);
    // ca_op + fused LN2 (y16=q2; q2 overlays attn -- per-block same-row overwrite, safe)
    gemm_ln<1, false><<<Q_ / 32, 256, 0, stream>>>(
        attn, wt_ca_op, ca_op_b, q1, nullptr, ln2_g, ln2_b,
        q2, nullptr, nullptr, Q_, 256);

    // ---- FFN ----
    gemm_lds<128, true, 0, false, false><<<dim3(Q_ / 128, 8), 256, 0, stream>>>(
        q2, nullptr, wt_ffn1, ffn_b1, nullptr, nullptr, hidden, Q_, 1024, 256,
        nullptr, nullptr, 0);
    gemm_lds<64, false, 1, false, false><<<dim3(Q_ / 64, 2), 256, 0, stream>>>(
        hidden, nullptr, wt_ffn2, ffn_b2, q2, nullptr, q1, Q_, 256, 1024,
        nullptr, nullptr, 0);
    // LN3 -> fp32 final output + folded out_qp copy (hidden region dead now)
    ln_kernel<true><<<Q_ / 4, 256, 0, stream>>>(
        q1, ln3_g, ln3_b, nullptr, out_q, nullptr, nullptr,
        (const float4*)qpos, (float4*)out_qp);

    (void)in_sizes; (void)n_in; (void)out_size; (void)ws_size;
}

// Round 14
// 469.202 us; speedup vs baseline: 1.0476x; 1.0284x over previous
//
#include <hip/hip_runtime.h>

// ---------------- problem constants ----------------
#define Q_   25600
#define C_   256
#define NH_  8
#define HD_  32
#define NP_  4
#define LC_  2
#define HW_  160          // H == W == 160

#define QC   (Q_ * C_)            // 6,553,600
#define VC   (2 * QC)             // 13,107,200
#define REFN (Q_ * LC_ * 2)       // 102,400

typedef unsigned short ushort_t;
typedef __attribute__((ext_vector_type(8))) short short8;
typedef __attribute__((ext_vector_type(4))) float f32x4;

// ---------------- bf16 helpers ----------------
__device__ __forceinline__ float b2f(ushort_t u) {
    union { unsigned int u32; float f; } c; c.u32 = ((unsigned int)u) << 16; return c.f;
}
__device__ __forceinline__ ushort_t f2b(float f) {
    union { float f; unsigned int u32; } c; c.f = f;
    unsigned int u = c.u32;
    return (ushort_t)((u + 0x7FFFu + ((u >> 16) & 1u)) >> 16);
}
__device__ __forceinline__ unsigned int pack2(float lo, float hi){
    return (unsigned int)f2b(lo) | ((unsigned int)f2b(hi) << 16);
}
__device__ __forceinline__ short8 pack8(float4 a, float4 b){
    union { short8 s; ushort_t u[8]; } r;
    r.u[0]=f2b(a.x); r.u[1]=f2b(a.y); r.u[2]=f2b(a.z); r.u[3]=f2b(a.w);
    r.u[4]=f2b(b.x); r.u[5]=f2b(b.y); r.u[6]=f2b(b.z); r.u[7]=f2b(b.w);
    return r.s;
}
__device__ __forceinline__ float uasf(unsigned int u){
    union { unsigned int u32; float f; } c; c.u32 = u; return c.f;
}
// unpack 4 bf16 (packed in uint2) -> 4 floats
__device__ __forceinline__ float4 unpk4(uint2 u){
    float4 r;
    r.x = uasf(u.x << 16); r.y = uasf(u.x & 0xFFFF0000u);
    r.z = uasf(u.y << 16); r.w = uasf(u.y & 0xFFFF0000u);
    return r;
}

// async global->LDS, 16 B per lane; LDS dest = wave-uniform base + lane*16
__device__ __forceinline__ void gload16(const void* g, void* l) {
    __builtin_amdgcn_global_load_lds(
        (const __attribute__((address_space(1))) void*)(uintptr_t)(g),
        (__attribute__((address_space(3))) void*)(uintptr_t)(l), 16, 0, 0);
}

// ---------------- prologue: qpq = bf16(query+qpos) + weight transposes (fp32->bf16)
// + (last block) ss int32->fp32 and concatenated off/aw bias vectors ----------------
struct TDesc { const float* src; ushort_t* dst; int K; int N; };
struct TAll  { TDesc t[10]; };

#define QC4   (QC / 4)        // 1,638,400
#define TRANS_TOTAL 860160
#define PRO_TOTAL (QC4 + TRANS_TOTAL)   // 2,498,560 (multiple of 256)

__global__ __launch_bounds__(256) void prologue_kernel(
    const float* __restrict__ query, const float* __restrict__ qpos,
    ushort_t* __restrict__ qpq, TAll td,
    const int* __restrict__ ss, float* __restrict__ out_ss,
    const float* __restrict__ sa_off_b, const float* __restrict__ sa_aw_b,
    const float* __restrict__ ca_off_b, const float* __restrict__ ca_aw_b,
    float* __restrict__ cb_sa, float* __restrict__ cb_ca)
{
    int i = blockIdx.x * 256 + threadIdx.x;
    if (i >= PRO_TOTAL) {
        int j = i - PRO_TOTAL;
        if (j < 4)   out_ss[j] = (float)ss[j];
        if (j < 96)  cb_sa[j] = (j < 64) ? sa_off_b[j] : sa_aw_b[j - 64];
        if (j < 192) cb_ca[j] = (j < 128) ? ca_off_b[j] : ca_aw_b[j - 128];
        return;
    }
    if (i < QC4) {
        float4 qv = ((const float4*)query)[i];
        float4 pv = ((const float4*)qpos)[i];
        uint2 o;
        o.x = pack2(qv.x + pv.x, qv.y + pv.y);
        o.y = pack2(qv.z + pv.z, qv.w + pv.w);
        ((uint2*)qpq)[i] = o;
        return;
    }
    i -= QC4;
    #pragma unroll 1
    for (int m = 0; m < 10; m++) {
        int sz = td.t[m].K * td.t[m].N;
        if (i < sz) {
            int N = td.t[m].N, K = td.t[m].K;
            int k = i / N, n = i - k * N;
            td.t[m].dst[(size_t)n * K + k] = f2b(td.t[m].src[i]);
            return;
        }
        i -= sz;
    }
}

// ---------------- LDS-staged MFMA GEMM body (m97 structure, BK=64 as 2x32 sub-stages) ----------------
// Tile BM x 128, 4 waves as 2x2. AF32: A staged fp32. RESM 0/1/2. VOUT head-major.
// cp*: grid-stride float4 copy over this segment (cpb = segment-local block id,
// cpnt = segment thread count).
template<int BM, bool RELU, int RESM, bool AF32, bool VOUT>
__device__ __forceinline__ void gemm_lds_body(
    char* smem, int bx, int by,
    const ushort_t* __restrict__ A16, const float* __restrict__ A32,
    const ushort_t* __restrict__ Bt, const float* __restrict__ bias,
    const ushort_t* __restrict__ res16, const float* __restrict__ res32,
    ushort_t* __restrict__ Cout, int M, int N, int K,
    const float4* __restrict__ cpsrc, float4* __restrict__ cpdst, int cpn,
    int cpb, int cpnt)
{
    constexpr int WM = BM / 2;                      // wave tile rows
    constexpr int MR = WM / 16;                     // A frags per wave
    constexpr int ASUB = BM * 32 * (AF32 ? 4 : 2);  // bytes per 32-col A sub-tile
    constexpr int BSUB = 128 * 32 * 2;              // bytes per 32-col B sub-tile
    char* lA = smem;                                // [2][BM][32]
    char* lB = smem + 2 * ASUB;                     // [2][128][32]

    const int lane = threadIdx.x & 63;
    const int wave = threadIdx.x >> 6;
    const int wm = wave >> 1, wn = wave & 1;
    const int m0 = bx * BM;
    const int n0 = by * 128;
    const int r = lane & 15, quad = lane >> 4;

    f32x4 acc[MR][4];
    #pragma unroll
    for (int i = 0; i < MR; i++)
        #pragma unroll
        for (int j = 0; j < 4; j++) acc[i][j] = (f32x4){0.f, 0.f, 0.f, 0.f};

    for (int k0 = 0; k0 < K; k0 += 64) {
        #pragma unroll
        for (int s = 0; s < 2; s++)
            #pragma unroll
            for (int t = 0; t < 2; t++) {
                int row = wave * 32 + t * 16;
                gload16(Bt + (size_t)(n0 + row + (lane >> 2)) * K + k0 + s * 32 + (lane & 3) * 8,
                        lB + s * BSUB + row * 64);
            }
        if (AF32) {
            #pragma unroll
            for (int s = 0; s < 2; s++)
                #pragma unroll
                for (int t = 0; t < BM / 32; t++) {
                    int row = wave * (BM / 4) + t * 8;
                    gload16(A32 + (size_t)(m0 + row + (lane >> 3)) * K + k0 + s * 32 + (lane & 7) * 4,
                            lA + s * ASUB + row * 128);
                }
        } else {
            #pragma unroll
            for (int s = 0; s < 2; s++)
                #pragma unroll
                for (int t = 0; t < BM / 64; t++) {
                    int row = wave * (BM / 4) + t * 16;
                    gload16(A16 + (size_t)(m0 + row + (lane >> 2)) * K + k0 + s * 32 + (lane & 3) * 8,
                            lA + s * ASUB + row * 64);
                }
        }
        __syncthreads();   // vmcnt(0) drain + barrier

        short8 af[2][MR], bf[2][4];
        #pragma unroll
        for (int s = 0; s < 2; s++) {
            #pragma unroll
            for (int i = 0; i < MR; i++) {
                int row = wm * WM + i * 16 + r;
                if (AF32) {
                    const float* p = (const float*)(lA + s * ASUB) + row * 32 + quad * 8;
                    float4 u = *(const float4*)p;
                    float4 v = *(const float4*)(p + 4);
                    af[s][i] = pack8(u, v);
                } else {
                    af[s][i] = *(const short8*)((const ushort_t*)(lA + s * ASUB) + row * 32 + quad * 8);
                }
            }
            #pragma unroll
            for (int j = 0; j < 4; j++) {
                int row = wn * 64 + j * 16 + r;
                bf[s][j] = *(const short8*)((const ushort_t*)(lB + s * BSUB) + row * 32 + quad * 8);
            }
        }
        #pragma unroll
        for (int s = 0; s < 2; s++)
            #pragma unroll
            for (int i = 0; i < MR; i++)
                #pragma unroll
                for (int j = 0; j < 4; j++)
                    acc[i][j] = __builtin_amdgcn_mfma_f32_16x16x32_bf16(af[s][i], bf[s][j], acc[i][j], 0, 0, 0);
        __syncthreads();
    }

    float bv[4];
    #pragma unroll
    for (int j = 0; j < 4; j++) bv[j] = bias[n0 + wn * 64 + j * 16 + r];

    #pragma unroll
    for (int i = 0; i < MR; i++) {
        int row = m0 + wm * WM + i * 16 + quad * 4;
        #pragma unroll
        for (int j = 0; j < 4; j++) {
            int col = n0 + wn * 64 + j * 16 + r;
            #pragma unroll
            for (int t = 0; t < 4; t++) {
                float v = acc[i][j][t] + bv[j];
                if (RESM == 1) v += b2f(res16[(size_t)(row + t) * N + col]);
                if (RESM == 2) v += res32[(size_t)(row + t) * N + col];
                if (RELU) v = fmaxf(v, 0.f);
                if (VOUT) {
                    Cout[((size_t)(col >> 5) * (size_t)M + (size_t)(row + t)) * HD_ + (col & 31)] = f2b(v);
                } else {
                    Cout[(size_t)(row + t) * N + col] = f2b(v);
                }
            }
        }
    }

    if (cpdst) {
        int tid = cpb * 256 + threadIdx.x;
        for (int i = tid; i < cpn; i += cpnt) cpdst[i] = cpsrc[i];
    }
}

// standalone wrapper (FFN1 / FFN2)
template<int BM, bool RELU, int RESM, bool AF32, bool VOUT>
__global__ __launch_bounds__(256) void gemm_lds(
    const ushort_t* __restrict__ A16, const float* __restrict__ A32,
    const ushort_t* __restrict__ Bt, const float* __restrict__ bias,
    const ushort_t* __restrict__ res16, const float* __restrict__ res32,
    ushort_t* __restrict__ Cout, int M, int N, int K)
{
    constexpr int ASUB = BM * 32 * (AF32 ? 4 : 2);
    __shared__ __align__(16) char smem[2 * ASUB + 2 * 128 * 32 * 2];
    gemm_lds_body<BM, RELU, RESM, AF32, VOUT>(
        smem, blockIdx.x, blockIdx.y, A16, A32, Bt, bias, res16, res32,
        Cout, M, N, K, nullptr, nullptr, 0, 0, 0);
}

// ---------------- reg-direct MFMA GEMM body (small-N fused off+aw) ----------------
template<int WN>
__device__ __forceinline__ void gemm_bf16_body(
    int bx, int by,
    const ushort_t* __restrict__ A16,
    const ushort_t* __restrict__ Bt, const float* __restrict__ bias,
    ushort_t* __restrict__ Cout, int M, int N, int K)
{
    const int lane = threadIdx.x & 63;
    const int wave = threadIdx.x >> 6;
    const int m0 = bx * 256 + wave * 64;
    const int n0 = by * (16 * WN);
    const int r = lane & 15, quad = lane >> 4;

    f32x4 acc[4][WN];
    #pragma unroll
    for (int i = 0; i < 4; i++)
        #pragma unroll
        for (int j = 0; j < WN; j++) acc[i][j] = (f32x4){0.f, 0.f, 0.f, 0.f};

    const ushort_t* Ab16 = A16 + (size_t)(m0 + r) * K + quad * 8;
    const ushort_t* Bbase = Bt + (size_t)(n0 + r) * K + quad * 8;

    for (int k0 = 0; k0 < K; k0 += 64) {
        short8 af0[4], af1[4], b0[WN], b1[WN];
        #pragma unroll
        for (int i = 0; i < 4; i++) {
            af0[i] = *(const short8*)(Ab16 + (size_t)i * 16 * K + k0);
            af1[i] = *(const short8*)(Ab16 + (size_t)i * 16 * K + k0 + 32);
        }
        #pragma unroll
        for (int j = 0; j < WN; j++) {
            b0[j] = *(const short8*)(Bbase + (size_t)j * 16 * K + k0);
            b1[j] = *(const short8*)(Bbase + (size_t)j * 16 * K + k0 + 32);
        }
        #pragma unroll
        for (int i = 0; i < 4; i++)
            #pragma unroll
            for (int j = 0; j < WN; j++)
                acc[i][j] = __builtin_amdgcn_mfma_f32_16x16x32_bf16(af0[i], b0[j], acc[i][j], 0, 0, 0);
        #pragma unroll
        for (int i = 0; i < 4; i++)
            #pragma unroll
            for (int j = 0; j < WN; j++)
                acc[i][j] = __builtin_amdgcn_mfma_f32_16x16x32_bf16(af1[i], b1[j], acc[i][j], 0, 0, 0);
    }

    float bv[WN];
    #pragma unroll
    for (int j = 0; j < WN; j++) bv[j] = bias[n0 + j * 16 + r];

    #pragma unroll
    for (int i = 0; i < 4; i++) {
        int row = m0 + i * 16 + quad * 4;
        #pragma unroll
        for (int j = 0; j < WN; j++) {
            int col = n0 + j * 16 + r;
            #pragma unroll
            for (int t = 0; t < 4; t++) {
                float v = acc[i][j][t] + bv[j];
                Cout[(size_t)(row + t) * N + col] = f2b(v);
            }
        }
    }
}

// standalone wrapper (ca off+aw)
template<int WN>
__global__ __launch_bounds__(256) void gemm_bf16(
    const ushort_t* __restrict__ A16,
    const ushort_t* __restrict__ Bt, const float* __restrict__ bias,
    ushort_t* __restrict__ Cout, int M, int N, int K)
{
    gemm_bf16_body<WN>(blockIdx.x, blockIdx.y, A16, Bt, bias, Cout, M, N, K);
}

// ---------------- MEGA1: sa_vp [0,400) | ca_vp [400,1200) | sa off+aw [1200,1300) ----------------
// All three depend only on the prologue -> co-scheduled in one dispatch so the
// BW-heavy out_val copy, latency-bound AF32 GEMMs, and reg-direct GEMM overlap.
__global__ __launch_bounds__(256) void mega1_kernel(
    const float* __restrict__ query, const float* __restrict__ value,
    const ushort_t* __restrict__ qpq,
    const ushort_t* __restrict__ wt_sa_vp, const float* __restrict__ sa_vp_b,
    const ushort_t* __restrict__ wt_ca_vp, const float* __restrict__ ca_vp_b,
    const ushort_t* __restrict__ wt_sa_off, const float* __restrict__ cb_sa_b,
    ushort_t* __restrict__ vbuf, ushort_t* __restrict__ cqa,
    const float4* __restrict__ ref4, float4* __restrict__ out_ref4,
    const float4* __restrict__ val4, float4* __restrict__ out_val4)
{
    __shared__ __align__(16) char smem[32768];   // AF32 BM=64: 2*8K A + 2*8K B
    const int bx = blockIdx.x, by = blockIdx.y;
    if (bx < 400) {
        // sa_vp (+ folded out_ref copy over this 800-block segment)
        gemm_lds_body<64, false, 0, true, true>(
            smem, bx, by, nullptr, query, wt_sa_vp, sa_vp_b, nullptr, nullptr,
            vbuf, Q_, 256, 256,
            ref4, out_ref4, REFN / 4, by * 400 + bx, 800 * 256);
    } else if (bx < 1200) {
        // ca_vp (+ folded out_val copy over this 1600-block segment)
        gemm_lds_body<64, false, 0, true, true>(
            smem, bx - 400, by, nullptr, value, wt_ca_vp, ca_vp_b, nullptr, nullptr,
            vbuf, 2 * Q_, 256, 256,
            val4, out_val4, VC / 4, by * 800 + (bx - 400), 1600 * 256);
    } else {
        // sa off+aw fused projection (N=96, WN=3)
        gemm_bf16_body<3>(bx - 1200, by, qpq, wt_sa_off, cb_sa_b, cqa, Q_, 96, 256);
    }
}

// ---------------- LDS-staged GEMM + fused LayerNorm (N=256, BM=32, 4 waves split cols) ----------------
// y16 = LN(A@B + bias + res) ; optional y2 = bf16(LN_out + qpos).
// RESM: 1 bf16 residual, 2 fp32 residual.
template<int RESM, bool Y2>
__global__ __launch_bounds__(256) void gemm_ln(
    const ushort_t* __restrict__ A16,
    const ushort_t* __restrict__ Bt, const float* __restrict__ bias,
    const ushort_t* __restrict__ res16, const float* __restrict__ res32,
    const float* __restrict__ lng, const float* __restrict__ lnb,
    ushort_t* __restrict__ y16,
    const float* __restrict__ qpos, ushort_t* __restrict__ y2,
    int M, int K)
{
    constexpr int ASUB = 32 * 32 * 2;    // 2 KB per 32-col A sub-tile
    constexpr int BSUB = 256 * 32 * 2;   // 16 KB per 32-col B sub-tile
    __shared__ __align__(16) char smem[2 * ASUB + 2 * BSUB];   // 36 KB
    char* lA = smem;
    char* lB = smem + 2 * ASUB;

    const int lane = threadIdx.x & 63;
    const int wave = threadIdx.x >> 6;   // column quarter
    const int m0 = blockIdx.x * 32;
    const int r = lane & 15, quad = lane >> 4;

    f32x4 acc[2][4];
    #pragma unroll
    for (int i = 0; i < 2; i++)
        #pragma unroll
        for (int j = 0; j < 4; j++) acc[i][j] = (f32x4){0.f, 0.f, 0.f, 0.f};

    for (int k0 = 0; k0 < K; k0 += 64) {
        {
            int s = wave >> 1;
            int row = (wave & 1) * 16 + (lane >> 2);
            gload16(A16 + (size_t)(m0 + row) * K + k0 + s * 32 + (lane & 3) * 8,
                    lA + s * ASUB + (wave & 1) * 1024);
        }
        #pragma unroll
        for (int s = 0; s < 2; s++)
            #pragma unroll
            for (int t = 0; t < 4; t++) {
                int row0 = wave * 64 + t * 16;
                gload16(Bt + (size_t)(row0 + (lane >> 2)) * K + k0 + s * 32 + (lane & 3) * 8,
                        lB + s * BSUB + row0 * 64);
            }
        __syncthreads();

        short8 af[2][2], bf[2][4];
        #pragma unroll
        for (int s = 0; s < 2; s++) {
            #pragma unroll
            for (int i = 0; i < 2; i++) {
                int row = i * 16 + r;
                af[s][i] = *(const short8*)((const ushort_t*)(lA + s * ASUB) + row * 32 + quad * 8);
            }
            #pragma unroll
            for (int j = 0; j < 4; j++) {
                int row = wave * 64 + j * 16 + r;
                bf[s][j] = *(const short8*)((const ushort_t*)(lB + s * BSUB) + row * 32 + quad * 8);
            }
        }
        #pragma unroll
        for (int s = 0; s < 2; s++)
            #pragma unroll
            for (int i = 0; i < 2; i++)
                #pragma unroll
                for (int j = 0; j < 4; j++)
                    acc[i][j] = __builtin_amdgcn_mfma_f32_16x16x32_bf16(af[s][i], bf[s][j], acc[i][j], 0, 0, 0);
        __syncthreads();
    }

    float bv[4];
    #pragma unroll
    for (int j = 0; j < 4; j++) bv[j] = bias[wave * 64 + j * 16 + r];

    float rs[2][4], rq[2][4];
    #pragma unroll
    for (int i = 0; i < 2; i++)
        #pragma unroll
        for (int t = 0; t < 4; t++) { rs[i][t] = 0.f; rq[i][t] = 0.f; }

    #pragma unroll
    for (int i = 0; i < 2; i++)
        #pragma unroll
        for (int j = 0; j < 4; j++) {
            int col = wave * 64 + j * 16 + r;
            #pragma unroll
            for (int t = 0; t < 4; t++) {
                int row = m0 + i * 16 + quad * 4 + t;
                float v = acc[i][j][t] + bv[j];
                if (RESM == 1) v += b2f(res16[(size_t)row * C_ + col]);
                if (RESM == 2) v += res32[(size_t)row * C_ + col];
                acc[i][j][t] = v;
                rs[i][t] += v; rq[i][t] += v * v;
            }
        }

    #pragma unroll
    for (int m = 1; m < 16; m <<= 1)
        #pragma unroll
        for (int i = 0; i < 2; i++)
            #pragma unroll
            for (int t = 0; t < 4; t++) {
                rs[i][t] += __shfl_xor(rs[i][t], m, 64);
                rq[i][t] += __shfl_xor(rq[i][t], m, 64);
            }

    float2* red = (float2*)smem;        // [32 rows][4 waves]
    if (r == 0) {
        #pragma unroll
        for (int i = 0; i < 2; i++)
            #pragma unroll
            for (int t = 0; t < 4; t++) {
                int lr = i * 16 + quad * 4 + t;
                red[lr * 4 + wave] = make_float2(rs[i][t], rq[i][t]);
            }
    }
    __syncthreads();

    float mn[2][4], ri[2][4];
    #pragma unroll
    for (int i = 0; i < 2; i++)
        #pragma unroll
        for (int t = 0; t < 4; t++) {
            int lr = i * 16 + quad * 4 + t;
            float s = 0.f, sq = 0.f;
            #pragma unroll
            for (int w = 0; w < 4; w++) { float2 p = red[lr * 4 + w]; s += p.x; sq += p.y; }
            float mean = s * (1.f / 256.f);
            float var  = sq * (1.f / 256.f) - mean * mean;
            mn[i][t] = mean;
            ri[i][t] = rsqrtf(fmaxf(var, 0.f) + 1e-5f);
        }

    float gv[4], bb[4];
    #pragma unroll
    for (int j = 0; j < 4; j++) {
        int col = wave * 64 + j * 16 + r;
        gv[j] = lng[col]; bb[j] = lnb[col];
    }

    #pragma unroll
    for (int i = 0; i < 2; i++)
        #pragma unroll
        for (int j = 0; j < 4; j++) {
            int col = wave * 64 + j * 16 + r;
            #pragma unroll
            for (int t = 0; t < 4; t++) {
                int row = m0 + i * 16 + quad * 4 + t;
                float vn = (acc[i][j][t] - mn[i][t]) * ri[i][t] * gv[j] + bb[j];
                y16[(size_t)row * C_ + col] = f2b(vn);
                if (Y2) y2[(size_t)row * C_ + col] = f2b(vn + qpos[(size_t)row * C_ + col]);
            }
        }
}

// ---------------- fused softmax + bilinear sampling (lane-split geometry) ----------------
template<int L>
__global__ __launch_bounds__(256) void sample_kernel(
    const ushort_t* __restrict__ v,    // head-major projected value (bf16)
    const ushort_t* __restrict__ cb,   // [Q, NH*L*NP*3] combined off+aw (bf16)
    const float*    __restrict__ ref,  // [Q, LC, 2] fp32
    ushort_t* __restrict__ outp)       // [Q, C] bf16
{
    const int t    = blockIdx.x * 256 + threadIdx.x;
    const int lane = threadIdx.x & 63;
    const int g    = t >> 3;           // (q,h) group
    const int sub  = t & 7;            // 4-channel slice; also own-point id
    const int q    = g >> 3;
    const int h    = g & 7;
    const int P    = L * NP_;
    const int STR  = NH_ * P * 3;      // 96 (L=1) or 192 (L=2)

    // ---- softmax over P logits (replicated; vectorized bf16 load) ----
    float w[2 * NP_];
    {
        union { uint4 q4; uint2 q2; ushort_t u[8]; } ab;
        const ushort_t* awp = cb + (size_t)q * STR + NH_ * P * 2 + h * P;
        if (L == 2) ab.q4 = *(const uint4*)awp;
        else        ab.q2 = *(const uint2*)awp;
        float mx = -1e30f;
        #pragma unroll
        for (int i = 0; i < P; i++) { w[i] = b2f(ab.u[i]); mx = fmaxf(mx, w[i]); }
        float s = 0.f;
        #pragma unroll
        for (int i = 0; i < P; i++) { w[i] = __expf(w[i] - mx); s += w[i]; }
        float inv = 1.f / s;
        #pragma unroll
        for (int i = 0; i < P; i++) w[i] *= inv;
    }

    // ---- own point geometry (one point per lane; L=1: lanes 4-7 duplicate 0-3) ----
    const int ip = (L == 2) ? sub : (sub & 3);
    float w00, w10, w01, w11;
    int   o00, o10, o01, o11;
    {
        unsigned int op = *(const unsigned int*)(cb + (size_t)q * STR + h * (P * 2) + ip * 2);
        float ox = b2f((ushort_t)(op & 0xFFFF)), oy = b2f((ushort_t)(op >> 16));
        int l = ip >> 2;   // 0 for L=1
        float rx = ref[((size_t)q * LC_ + l) * 2 + 0] * (float)HW_ - 0.5f;
        float ry = ref[((size_t)q * LC_ + l) * 2 + 1] * (float)HW_ - 0.5f;
        float x = fminf(fmaxf(rx + ox, -1e4f), 1e4f);
        float y = fminf(fmaxf(ry + oy, -1e4f), 1e4f);
        float xf = floorf(x), yf = floorf(y);
        float tx = x - xf, ty = y - yf;
        int x0 = (int)xf, y0 = (int)yf;
        int x1 = x0 + 1, y1 = y0 + 1;
        int xc0 = min(max(x0, 0), HW_ - 1), xc1 = min(max(x1, 0), HW_ - 1);
        int yc0 = min(max(y0, 0), HW_ - 1), yc1 = min(max(y1, 0), HW_ - 1);
        bool vx0 = (unsigned)x0 < (unsigned)HW_, vx1 = (unsigned)x1 < (unsigned)HW_;
        bool vy0 = (unsigned)y0 < (unsigned)HW_, vy1 = (unsigned)y1 < (unsigned)HW_;
        float aww = w[ip];
        float ax0 = (1.f - tx) * aww, ax1 = tx * aww;
        w00 = ax0 * (1.f - ty); w10 = ax1 * (1.f - ty);
        w01 = ax0 * ty;         w11 = ax1 * ty;
        w00 = (vx0 & vy0) ? w00 : 0.f;
        w10 = (vx1 & vy0) ? w10 : 0.f;
        w01 = (vx0 & vy1) ? w01 : 0.f;
        w11 = (vx1 & vy1) ? w11 : 0.f;
        int r0 = yc0 * HW_, r1 = yc1 * HW_;
        o00 = (r0 + xc0) * HD_; o10 = (r0 + xc1) * HD_;
        o01 = (r1 + xc0) * HD_; o11 = (r1 + xc1) * HD_;
    }

    const ushort_t* vh = v + ((size_t)(h * L) * Q_) * HD_ + sub * 4;
    const int gbase = lane & ~7;
    float4 acc = {0.f, 0.f, 0.f, 0.f};

    #pragma unroll
    for (int p = 0; p < P; p++) {
        int src = gbase | p;           // owner lane of point p (L=1: p<4)
        float a00 = __shfl(w00, src, 64), a10 = __shfl(w10, src, 64);
        float a01 = __shfl(w01, src, 64), a11 = __shfl(w11, src, 64);
        int   b00 = __shfl(o00, src, 64), b10 = __shfl(o10, src, 64);
        int   b01 = __shfl(o01, src, 64), b11 = __shfl(o11, src, 64);
        const ushort_t* vl = vh + (size_t)(p >> 2) * ((size_t)Q_ * HD_);
        uint2 u00 = *(const uint2*)(vl + b00);
        uint2 u10 = *(const uint2*)(vl + b10);
        uint2 u01 = *(const uint2*)(vl + b01);
        uint2 u11 = *(const uint2*)(vl + b11);
        float4 c00 = unpk4(u00), c10 = unpk4(u10), c01 = unpk4(u01), c11 = unpk4(u11);
        acc.x += c00.x * a00 + c10.x * a10 + c01.x * a01 + c11.x * a11;
        acc.y += c00.y * a00 + c10.y * a10 + c01.y * a01 + c11.y * a11;
        acc.z += c00.z * a00 + c10.z * a10 + c01.z * a01 + c11.z * a11;
        acc.w += c00.w * a00 + c10.w * a10 + c01.w * a01 + c11.w * a11;
    }

    uint2 o;
    o.x = pack2(acc.x, acc.y);
    o.y = pack2(acc.z, acc.w);
    *(uint2*)(outp + (size_t)q * C_ + h * HD_ + sub * 4) = o;
}

// ---------------- LayerNorm (wave per row of 256) -- used only for LN3 ----------------
template<bool OUT32>
__global__ __launch_bounds__(256) void ln_kernel(
    const ushort_t* __restrict__ x, const float* __restrict__ g,
    const float* __restrict__ b, ushort_t* __restrict__ y16,
    float* __restrict__ y32,
    const float* __restrict__ qpos, ushort_t* __restrict__ y2,
    const float4* __restrict__ cpsrc, float4* __restrict__ cpdst)
{
    const int lane = threadIdx.x & 63;
    const int wave = threadIdx.x >> 6;
    const size_t row = (size_t)blockIdx.x * 4 + wave;
    const size_t base = row * C_ + lane * 4;

    uint2 xv = *(const uint2*)(x + base);
    float f0 = b2f((ushort_t)(xv.x & 0xFFFF)), f1 = b2f((ushort_t)(xv.x >> 16));
    float f2 = b2f((ushort_t)(xv.y & 0xFFFF)), f3 = b2f((ushort_t)(xv.y >> 16));
    float s  = f0 + f1 + f2 + f3;
    float sq = f0 * f0 + f1 * f1 + f2 * f2 + f3 * f3;
    #pragma unroll
    for (int m = 1; m < 64; m <<= 1) { s += __shfl_xor(s, m, 64); sq += __shfl_xor(sq, m, 64); }
    float mean = s * (1.f / 256.f);
    float var  = sq * (1.f / 256.f) - mean * mean;
    float rinv = rsqrtf(fmaxf(var, 0.f) + 1e-5f);

    float4 gv = *(const float4*)(g + lane * 4);
    float4 bv = *(const float4*)(b + lane * 4);
    float o0 = (f0 - mean) * rinv * gv.x + bv.x;
    float o1 = (f1 - mean) * rinv * gv.y + bv.y;
    float o2 = (f2 - mean) * rinv * gv.z + bv.z;
    float o3 = (f3 - mean) * rinv * gv.w + bv.w;

    if (OUT32) {
        float4 o; o.x = o0; o.y = o1; o.z = o2; o.w = o3;
        *(float4*)(y32 + base) = o;
    } else {
        uint2 ov; ov.x = pack2(o0, o1); ov.y = pack2(o2, o3);
        *(uint2*)(y16 + base) = ov;
    }

    if (y2) {
        float4 pv = *(const float4*)(qpos + base);
        uint2 o2v;
        o2v.x = pack2(o0 + pv.x, o1 + pv.y);
        o2v.y = pack2(o2 + pv.z, o3 + pv.w);
        *(uint2*)(y2 + base) = o2v;
    }

    if (cpdst) {
        int tid = blockIdx.x * 256 + threadIdx.x;
        cpdst[tid] = cpsrc[tid];
    }
}

// ---------------- host ----------------
extern "C" void kernel_launch(void* const* d_in, const int* in_sizes, int n_in,
                              void* d_out, int out_size, void* d_ws, size_t ws_size,
                              hipStream_t stream)
{
    const float* query = (const float*)d_in[0];
    const float* qpos  = (const float*)d_in[1];
    const float* value = (const float*)d_in[2];
    const float* ref   = (const float*)d_in[3];
    const int*   ss    = (const int*)d_in[4];
    const float* sa_off_w = (const float*)d_in[5];
    const float* sa_off_b = (const float*)d_in[6];
    const float* sa_aw_w  = (const float*)d_in[7];
    const float* sa_aw_b  = (const float*)d_in[8];
    const float* sa_vp_w  = (const float*)d_in[9];
    const float* sa_vp_b  = (const float*)d_in[10];
    const float* sa_op_w  = (const float*)d_in[11];
    const float* sa_op_b  = (const float*)d_in[12];
    const float* ca_off_w = (const float*)d_in[13];
    const float* ca_off_b = (const float*)d_in[14];
    const float* ca_aw_w  = (const float*)d_in[15];
    const float* ca_aw_b  = (const float*)d_in[16];
    const float* ca_vp_w  = (const float*)d_in[17];
    const float* ca_vp_b  = (const float*)d_in[18];
    const float* ca_op_w  = (const float*)d_in[19];
    const float* ca_op_b  = (const float*)d_in[20];
    const float* ffn_w1   = (const float*)d_in[21];
    const float* ffn_b1   = (const float*)d_in[22];
    const float* ffn_w2   = (const float*)d_in[23];
    const float* ffn_b2   = (const float*)d_in[24];
    const float* ln1_g = (const float*)d_in[25];
    const float* ln1_b = (const float*)d_in[26];
    const float* ln2_g = (const float*)d_in[27];
    const float* ln2_b = (const float*)d_in[28];
    const float* ln3_g = (const float*)d_in[29];
    const float* ln3_b = (const float*)d_in[30];

    // ---- final output layout (fp32) ----
    float* outf    = (float*)d_out;
    float* out_q   = outf;                            // [Q,C]   bytes [0, 26.2M)
    float* out_qp  = outf + QC;                       // [Q,C]   bytes [26.2M, 52.4M)
    float* out_val = outf + 2 * (size_t)QC;           // [2Q,C]  bytes [52.4M, 104.9M)
    float* out_ref = outf + 4 * (size_t)QC;           // [Q,LC,2]
    float* out_ss  = outf + 4 * (size_t)QC + REFN;    // [4]

    // ---- d_out doubles as bf16 body scratch; scratch in bytes [0, 52.4M) ----
    ushort_t* dsc    = (ushort_t*)d_out;
    ushort_t* vbuf   = dsc;                           // 2QC bf16 (head-major value)
    ushort_t* cqa    = dsc + 3 * (size_t)QC;          // Q*192 bf16 max (combined off+aw)
    ushort_t* hidden = dsc;                           // Q*1024 bf16

    // ---- workspace ----
    char* base = (char*)d_ws;
    size_t offbyte = 0;
    auto alloc = [&](size_t elems) -> ushort_t* {
        ushort_t* p = (ushort_t*)(base + offbyte);
        offbyte += ((elems * 2 + 255) / 256) * 256;
        return p;
    };
    ushort_t* wt_sa_off = alloc(256 * 64);
    ushort_t* wt_sa_aw  = alloc(256 * 32);
    ushort_t* wt_sa_vp  = alloc(256 * 256);
    ushort_t* wt_sa_op  = alloc(256 * 256);
    ushort_t* wt_ca_off = alloc(256 * 128);
    ushort_t* wt_ca_aw  = alloc(256 * 64);
    ushort_t* wt_ca_vp  = alloc(256 * 256);
    ushort_t* wt_ca_op  = alloc(256 * 256);
    ushort_t* wt_ffn1   = alloc(256 * 1024);
    ushort_t* wt_ffn2   = alloc(1024 * 256);
    ushort_t* qpq  = alloc(QC);     // bf16(q+pos), then bf16(ln1+pos)
    ushort_t* attn = alloc(QC);     // sampled attention out; later q2 (LN2 out)
    ushort_t* q1   = alloc(QC);     // LN1 out; later FFN2 out
    ushort_t* q2   = attn;          // LN2 out overlays dead attn (same-block rows, safe)
    float* cb_sa_b = (float*)alloc(192);
    float* cb_ca_b = (float*)alloc(384);

    TAll td;
    const float* srcs[10] = {sa_off_w, sa_aw_w, sa_vp_w, sa_op_w, ca_off_w,
                             ca_aw_w, ca_vp_w, ca_op_w, ffn_w1, ffn_w2};
    ushort_t* dsts[10] = {wt_sa_off, wt_sa_aw, wt_sa_vp, wt_sa_op, wt_ca_off,
                          wt_ca_aw, wt_ca_vp, wt_ca_op, wt_ffn1, wt_ffn2};
    int Ks[10] = {256, 256, 256, 256, 256, 256, 256, 256, 256, 1024};
    int Ns[10] = {64, 32, 256, 256, 128, 64, 256, 256, 1024, 256};
    for (int m = 0; m < 10; m++) { td.t[m] = {srcs[m], dsts[m], Ks[m], Ns[m]}; }

    // 1. prologue (+1 block: ss->fp32 + concat bias vectors)
    prologue_kernel<<<PRO_TOTAL / 256 + 1, 256, 0, stream>>>(
        query, qpos, qpq, td, ss, out_ss,
        sa_off_b, sa_aw_b, ca_off_b, ca_aw_b, cb_sa_b, cb_ca_b);

    // 2. MEGA1: sa_vp + ca_vp + sa off/aw (all depend only on prologue)
    mega1_kernel<<<dim3(1300, 2), 256, 0, stream>>>(
        query, value, qpq,
        wt_sa_vp, sa_vp_b, wt_ca_vp, ca_vp_b, wt_sa_off, cb_sa_b,
        vbuf, cqa,
        (const float4*)ref, (float4*)out_ref,
        (const float4*)value, (float4*)out_val);

    // ---- self-attention tail ----
    sample_kernel<1><<<(Q_ * NH_) / 32, 256, 0, stream>>>(vbuf, cqa, ref, attn);
    // sa_op + fused LN1 (y16=q1, y2=qpq=bf16(ln1+qpos))
    gemm_ln<2, true><<<Q_ / 32, 256, 0, stream>>>(
        attn, wt_sa_op, sa_op_b, nullptr, query, ln1_g, ln1_b,
        q1, qpos, qpq, Q_, 256);

    // ---- cross-attention ----
    gemm_bf16<3><<<dim3(Q_ / 256, 4), 256, 0, stream>>>(
        qpq, wt_ca_off, cb_ca_b, cqa, Q_, 192, 256);
    sample_kernel<2><<<(Q_ * NH_) / 32, 256, 0, stream>>>(vbuf, cqa, ref, attn);
    // ca_op + fused LN2 (y16=q2; q2 overlays attn -- per-block same-row overwrite, safe)
    gemm_ln<1, false><<<Q_ / 32, 256, 0, stream>>>(
        attn, wt_ca_op, ca_op_b, q1, nullptr, ln2_g, ln2_b,
        q2, nullptr, nullptr, Q_, 256);

    // ---- FFN ----
    gemm_lds<128, true, 0, false, false><<<dim3(Q_ / 128, 8), 256, 0, stream>>>(
        q2, nullptr, wt_ffn1, ffn_b1, nullptr, nullptr, hidden, Q_, 1024, 256);
    gemm_lds<64, false, 1, false, false><<<dim3(Q_ / 64, 2), 256, 0, stream>>>(
        hidden, nullptr, wt_ffn2, ffn_b2, q2, nullptr, q1, Q_, 256, 1024);
    // LN3 -> fp32 final output + folded out_qp copy (hidden region dead now)
    ln_kernel<true><<<Q_ / 4, 256, 0, stream>>>(
        q1, ln3_g, ln3_b, nullptr, out_q, nullptr, nullptr,
        (const float4*)qpos, (float4*)out_qp);

    (void)in_sizes; (void)n_in; (void)out_size; (void)ws_size;
}